// Round 2
// 300.241 us; speedup vs baseline: 1.0278x; 1.0278x over previous
//
#include <hip/hip_runtime.h>
#include <math.h>

// Problem constants
#define T_SEQ 2048
#define CDIM  1024
#define NH    16
#define DHD   64
#define BATCH 4
#define MROWS (BATCH * T_SEQ)   // 8192
#define BHN   (BATCH * NH)      // 64

typedef _Float16 f16;
typedef __attribute__((ext_vector_type(8))) _Float16 f16x8;
typedef __attribute__((ext_vector_type(4))) _Float16 f16x4;
typedef __attribute__((ext_vector_type(2))) _Float16 f16x2;
typedef __attribute__((ext_vector_type(2))) __fp16 fp16x2;
typedef __attribute__((ext_vector_type(4))) float f32x4;

__device__ __forceinline__ float fast_exp2(float x) {
#if __has_builtin(__builtin_amdgcn_exp2f)
    return __builtin_amdgcn_exp2f(x);
#else
    return exp2f(x);
#endif
}

// packed f32x2 -> f16x2 convert (v_cvt_pkrtz_f16_f32)
__device__ __forceinline__ f16x2 cvt_pk_f16(float a, float b) {
    fp16x2 r = __builtin_amdgcn_cvt_pkrtz(a, b);
    return __builtin_bit_cast(f16x2, r);
}

// async global->LDS, 16B per lane; LDS dest = wave-uniform base + lane*16
__device__ __forceinline__ void gl_lds16(const f16* g, f16* l) {
    __builtin_amdgcn_global_load_lds(
        (const __attribute__((address_space(1))) void*)(g),
        (__attribute__((address_space(3))) void*)(l),
        16, 0, 0);
}

// ---------------------------------------------------------------------------
// RoPE trig tables (fp64 math)
// ---------------------------------------------------------------------------
__global__ void rope_tables_kernel(float* __restrict__ ctab, float* __restrict__ stab)
{
    int idx = blockIdx.x * 256 + threadIdx.x;   // 0 .. 2048*32-1
    int t = idx >> 5, i = idx & 31;
    double inv = pow(10000.0, -(double)(2 * i) / 64.0);
    double a = (double)t * inv;
    ctab[idx] = (float)cos(a);
    stab[idx] = (float)sin(a);
}

// ---------------------------------------------------------------------------
// X convert: fp32 [8192][1024] -> f16, same layout. 8 elems/thread.
// ---------------------------------------------------------------------------
__global__ __launch_bounds__(256) void xcvt_kernel(
    const float* __restrict__ X, f16* __restrict__ Xf)
{
    int idx = blockIdx.x * 256 + threadIdx.x;   // 8-elem chunk index
    const float4* src = (const float4*)X + (size_t)idx * 2;
    float4 a = src[0], b = src[1];
    f16x8 o;
    o[0] = (f16)a.x; o[1] = (f16)a.y; o[2] = (f16)a.z; o[3] = (f16)a.w;
    o[4] = (f16)b.x; o[5] = (f16)b.y; o[6] = (f16)b.z; o[7] = (f16)b.w;
    *((f16x8*)Xf + idx) = o;
}

// ---------------------------------------------------------------------------
// W transpose+convert: W [K][N] fp32 -> Wt [N][K] f16 (K=1024)
// ---------------------------------------------------------------------------
__global__ __launch_bounds__(64) void wcvt_kernel(
    const float* __restrict__ W, f16* __restrict__ Wt, int N)
{
    int lane = threadIdx.x;
    int k0 = blockIdx.x * 8;
    int n = blockIdx.y * 64 + lane;
    f16x8 o;
#pragma unroll
    for (int j = 0; j < 8; j++) o[j] = (f16)W[(size_t)(k0 + j) * N + n];
    *(f16x8*)(Wt + (size_t)n * CDIM + k0) = o;
}

// ---------------------------------------------------------------------------
// f16 MFMA GEMM mainloop: C[128x128] = A[128xK] B_t[128xK], K=1024
// ---------------------------------------------------------------------------
#define GEMM_MAINLOOP(Aimg, Bimg, M0, N0)                                         \
    __shared__ f16 As[128][32], Bs[128][32];                                      \
    const int tid = threadIdx.x, wave = tid >> 6, lane = tid & 63;                \
    const int l16 = lane & 15, quad = lane >> 4;                                  \
    const int wm = wave >> 1, wn = wave & 1;                                      \
    f32x4 acc[4][4];                                                              \
    _Pragma("unroll") for (int i = 0; i < 4; i++)                                 \
        _Pragma("unroll") for (int j = 0; j < 4; j++)                             \
            acc[i][j] = (f32x4){0.f, 0.f, 0.f, 0.f};                              \
    const f16* sbase = (wave < 2) ? (Aimg) : (Bimg);                              \
    f16* lbase = ((wave < 2) ? &As[0][0] : &Bs[0][0]) + (wave & 1) * 2048;        \
    const size_t srow0 = ((wave < 2) ? (size_t)(M0) : (size_t)(N0)) + (wave & 1) * 64; \
    const int srow = lane >> 2, schunk = (lane & 3) << 3;                         \
    for (int k0 = 0; k0 < CDIM; k0 += 32) {                                       \
        _Pragma("unroll") for (int it = 0; it < 4; it++)                          \
            gl_lds16(sbase + (srow0 + it * 16 + srow) * CDIM + k0 + schunk,       \
                     lbase + it * 512);                                           \
        __syncthreads();                                                          \
        f16x8 fa[4], fb[4];                                                       \
        _Pragma("unroll") for (int mi = 0; mi < 4; mi++)                          \
            fa[mi] = *(const f16x8*)&As[wm * 64 + mi * 16 + l16][quad * 8];       \
        _Pragma("unroll") for (int ni = 0; ni < 4; ni++)                          \
            fb[ni] = *(const f16x8*)&Bs[wn * 64 + ni * 16 + l16][quad * 8];       \
        _Pragma("unroll") for (int mi = 0; mi < 4; mi++)                          \
            _Pragma("unroll") for (int ni = 0; ni < 4; ni++)                      \
                acc[mi][ni] = __builtin_amdgcn_mfma_f32_16x16x32_f16(             \
                    fa[mi], fb[ni], acc[mi][ni], 0, 0, 0);                        \
        __syncthreads();                                                          \
    }

// ---------------------------------------------------------------------------
// QKV GEMM (f16 MFMA), fused bias + RoPE; writes q/k/v f16 in [bh][t][d].
// Q is pre-scaled by (1/8)*log2(e)  -->  attn uses exp2 directly.
// ---------------------------------------------------------------------------
__global__ __launch_bounds__(256) void qkv_gemm_kernel(
    const f16* __restrict__ Xf, const f16* __restrict__ Wt,
    const float* __restrict__ bias,
    const float* __restrict__ ctab, const float* __restrict__ stab,
    f16* __restrict__ qf, f16* __restrict__ kf, f16* __restrict__ vf)
{
    const int m0 = blockIdx.x * 128;
    const int n0 = blockIdx.y * 128;
    GEMM_MAINLOOP(Xf, Wt, m0, n0)

    const int ncol0 = n0 + wn * 64;            // 64-aligned -> one head group
    const int w = ncol0 >> 10;                 // 0=q 1=k 2=v
    const int h = (ncol0 >> 6) & 15;
    const int b = m0 >> 11;
    const int trow0 = (m0 & 2047) + wm * 64 + quad * 4;
    float bia[4];
#pragma unroll
    for (int ni = 0; ni < 4; ni++) bia[ni] = bias[ncol0 + ni * 16 + l16];

    if (w < 2) {
        f16* oq = w ? kf : qf;
        // q scale folds softmax 1/8 AND log2(e) so attn can use v_exp (2^x)
        const float sc = w ? 1.0f : 0.18033688011112042f;
#pragma unroll
        for (int mi = 0; mi < 4; mi++) {
#pragma unroll
            for (int i = 0; i < 4; i++) {
                int t = trow0 + mi * 16 + i;
                size_t rowoff = ((size_t)(b * NH + h) * T_SEQ + t) * DHD;
#pragma unroll
                for (int np = 0; np < 2; np++) {
                    int d = np * 16 + l16;             // 0..31
                    float v0 = acc[mi][np][i] + bia[np];
                    float v1 = acc[mi][np + 2][i] + bia[np + 2];
                    float c = ctab[(t << 5) + d];
                    float s = stab[(t << 5) + d];
                    oq[rowoff + d]      = (f16)((v0 * c - v1 * s) * sc);
                    oq[rowoff + d + 32] = (f16)((v1 * c + v0 * s) * sc);
                }
            }
        }
    } else {
#pragma unroll
        for (int mi = 0; mi < 4; mi++) {
#pragma unroll
            for (int i = 0; i < 4; i++) {
                int t = trow0 + mi * 16 + i;
                size_t rowoff = ((size_t)(b * NH + h) * T_SEQ + t) * DHD;
#pragma unroll
                for (int ni = 0; ni < 4; ni++)
                    vf[rowoff + ni * 16 + l16] = (f16)(acc[mi][ni][i] + bia[ni]);
            }
        }
    }
}

// ---------------------------------------------------------------------------
// V transpose: vf [bh][t][d] f16 -> vt [bh][d][t] f16
// ---------------------------------------------------------------------------
__global__ __launch_bounds__(256) void vt_kernel(
    const f16* __restrict__ vf, f16* __restrict__ vt)
{
    __shared__ f16 Ls[64][72];
    const int tid = threadIdx.x;
    const int tb = blockIdx.x;   // 0..31
    const int bh = blockIdx.y;   // 0..63
#pragma unroll
    for (int p = 0; p < 2; p++) {
        int idx = tid + p * 256;
        int r = idx >> 3, c8 = (idx & 7) << 3;
        *(f16x8*)&Ls[r][c8] =
            *(const f16x8*)(vf + ((size_t)bh * T_SEQ + tb * 64 + r) * DHD + c8);
    }
    __syncthreads();
#pragma unroll
    for (int p = 0; p < 2; p++) {
        int idx = tid + p * 256;
        int d = idx >> 3, t8 = (idx & 7) << 3;
        f16x8 o;
#pragma unroll
        for (int j = 0; j < 8; j++) o[j] = Ls[t8 + j][d];
        *(f16x8*)(vt + ((size_t)bh * DHD + d) * T_SEQ + (size_t)tb * 64 + t8) = o;
    }
}

// ---------------------------------------------------------------------------
// f16 MFMA flash attention v2:
//  - 128-query blocks, 4 waves x 32 queries; grid 16x64 = 1024 blocks
//    = 4 blocks/CU (LDS = 40960B exactly -> 4/CU, 16 waves/CU, no tail)
//  - XOR chunk-swizzled, UNPADDED K/V/P LDS tiles (conflict-free b128 reads,
//    reg-staged writes so swizzle is legal on both sides)
//  - exp2-direct softmax (log2e folded into Q), cvt_pkrtz f16 packing
//  - l accumulated by MFMA against a constant-ones B-fragment: no v_add
//    chain, no shuffle reduce, no Lb; 1/l is lane-local in the epilogue
//  - XCD-chunked block swizzle: each XCD's blocks share 8 heads (4MB = L2)
// ---------------------------------------------------------------------------
__global__ __launch_bounds__(256, 4) void attn_kernel(
    const f16* __restrict__ qf, const f16* __restrict__ kf,
    const f16* __restrict__ vt, f16* __restrict__ ab)
{
    __shared__ f16 Kb[2][64][64];     // [buf][key][d]   16384B, chunk-swizzled
    __shared__ f16 Vb[2][64][64];     // [buf][d][key]   16384B, chunk-swizzled
    __shared__ f16 Pb[4][32][32];     // per-wave [query][key%32] 8192B, swz
    // total 40960B -> exactly 4 blocks/CU

    const int tid  = threadIdx.x;
    const int wave = tid >> 6, lane = tid & 63;
    const int l16  = lane & 15, quad = lane >> 4;

    // XCD-chunked swizzle: flat id -> (qt, bh) so XCD x holds bh in [8x, 8x+8)
    const int flat = blockIdx.x + (blockIdx.y << 4);     // 0..1023
    const int swz  = (flat & 7) * 128 + (flat >> 3);     // bijective (1024%8==0)
    const int qt = swz & 15;                             // 0..15
    const int bh = swz >> 4;                             // 0..63
    const int q0 = qt * 128 + wave * 32;                 // wave's query base

    const f16* kbase = kf + (size_t)bh * T_SEQ * DHD;
    const f16* vbase = vt + (size_t)bh * DHD * T_SEQ;

    // Q B-frags [qsub][ks]: B[n=query=l16][k=d=quad*8+j]
    f16x8 qfr[2][2];
#pragma unroll
    for (int qs = 0; qs < 2; qs++) {
        const f16* qrow = qf + ((size_t)bh * T_SEQ + q0 + qs * 16 + l16) * DHD;
        qfr[qs][0] = *(const f16x8*)(qrow + quad * 8);
        qfr[qs][1] = *(const f16x8*)(qrow + 32 + quad * 8);
    }

    f32x4 o[2][4];      // [qsub][dt], C-layout row=query col=d
    f32x4 lacc[2];      // l partials, same row layout as o
#pragma unroll
    for (int qs = 0; qs < 2; qs++) {
        lacc[qs] = (f32x4){0.f, 0.f, 0.f, 0.f};
#pragma unroll
        for (int dt = 0; dt < 4; dt++) o[qs][dt] = (f32x4){0.f, 0.f, 0.f, 0.f};
    }
    f16x8 ones;
#pragma unroll
    for (int j = 0; j < 8; j++) ones[j] = (f16)1.0f;

    // staging map: 256 threads x 2 rounds x b128 = 8KB per array per tile
    const int srow = tid >> 3;                       // 0..31
    const int scw  = tid & 7;                        // chunk 0..7
    const int scol = scw << 3;                       // global f16 col
    const int swzc = (scw ^ (srow & 7)) << 3;        // swizzled LDS f16 col

    f16x8 kreg[2], vreg[2];
#pragma unroll
    for (int r = 0; r < 2; r++) {
        kreg[r] = *(const f16x8*)(kbase + (size_t)(srow + r * 32) * DHD + scol);
        vreg[r] = *(const f16x8*)(vbase + (size_t)(srow + r * 32) * T_SEQ + scol);
    }
#pragma unroll
    for (int r = 0; r < 2; r++) {
        *(f16x8*)&Kb[0][srow + r * 32][swzc] = kreg[r];
        *(f16x8*)&Vb[0][srow + r * 32][swzc] = vreg[r];
    }
    __syncthreads();

    for (int kt = 0; kt < 32; kt++) {
        const int buf = kt & 1;
        if (kt < 31) {   // prefetch next tile into registers (no wait)
#pragma unroll
            for (int r = 0; r < 2; r++) {
                kreg[r] = *(const f16x8*)(kbase + (size_t)((kt + 1) * 64 + srow + r * 32) * DHD + scol);
                vreg[r] = *(const f16x8*)(vbase + (size_t)(srow + r * 32) * T_SEQ + (kt + 1) * 64 + scol);
            }
        }

#pragma unroll
        for (int half = 0; half < 2; half++) {
            // ---- S^T for 32 keys x 32 queries ----
            f32x4 sc[2][2];   // [keysub][qsub]
#pragma unroll
            for (int k2 = 0; k2 < 2; k2++)
#pragma unroll
                for (int qs = 0; qs < 2; qs++) sc[k2][qs] = (f32x4){0.f, 0.f, 0.f, 0.f};
#pragma unroll
            for (int k2 = 0; k2 < 2; k2++) {
                const int keyt = half * 2 + k2;
#pragma unroll
                for (int ks = 0; ks < 2; ks++) {
                    const int kc = ((ks * 4 + quad) ^ (l16 & 7)) << 3;
                    f16x8 kfr = *(const f16x8*)&Kb[buf][keyt * 16 + l16][kc];
#pragma unroll
                    for (int qs = 0; qs < 2; qs++)
                        sc[k2][qs] = __builtin_amdgcn_mfma_f32_16x16x32_f16(
                            kfr, qfr[qs][ks], sc[k2][qs], 0, 0, 0);
                }
            }
            // ---- exp2 (log2e pre-folded), pack P via cvt_pkrtz, b64 writes ----
#pragma unroll
            for (int k2 = 0; k2 < 2; k2++) {
#pragma unroll
                for (int qs = 0; qs < 2; qs++) {
                    f16x2 pa = cvt_pk_f16(
                        fast_exp2(sc[k2][qs][0]), fast_exp2(sc[k2][qs][1]));
                    f16x2 pb = cvt_pk_f16(
                        fast_exp2(sc[k2][qs][2]), fast_exp2(sc[k2][qs][3]));
                    f16x4 pv;
                    ((f16x2*)&pv)[0] = pa;
                    ((f16x2*)&pv)[1] = pb;
                    const int pc = (((k2 * 2 + (quad >> 1)) ^ (l16 & 3)) << 3)
                                 + ((quad & 1) << 2);
                    *(f16x4*)&Pb[wave][qs * 16 + l16][pc] = pv;
                }
            }
            // ---- P frags; l += P*ones (MFMA); PV for this 32-key chunk ----
            f16x8 pfr[2];
            const int prc = (quad ^ (l16 & 3)) << 3;
#pragma unroll
            for (int qs = 0; qs < 2; qs++) {
                pfr[qs] = *(const f16x8*)&Pb[wave][qs * 16 + l16][prc];
                lacc[qs] = __builtin_amdgcn_mfma_f32_16x16x32_f16(
                    pfr[qs], ones, lacc[qs], 0, 0, 0);
            }
#pragma unroll
            for (int dt = 0; dt < 4; dt++) {
                const int vc = ((half * 4 + quad) ^ (l16 & 7)) << 3;
                f16x8 vfr = *(const f16x8*)&Vb[buf][dt * 16 + l16][vc];
#pragma unroll
                for (int qs = 0; qs < 2; qs++)
                    o[qs][dt] = __builtin_amdgcn_mfma_f32_16x16x32_f16(
                        pfr[qs], vfr, o[qs][dt], 0, 0, 0);
            }
        }

        if (kt < 31) {   // write prefetched tile into the other buffer
#pragma unroll
            for (int r = 0; r < 2; r++) {
                *(f16x8*)&Kb[buf ^ 1][srow + r * 32][swzc] = kreg[r];
                *(f16x8*)&Vb[buf ^ 1][srow + r * 32][swzc] = vreg[r];
            }
        }
        __syncthreads();
    }

    // ---- epilogue: normalize by lane-local 1/l, write ab[q][h*64+d] ----
    const int b = bh >> 4, h = bh & 15;
#pragma unroll
    for (int qs = 0; qs < 2; qs++) {
#pragma unroll
        for (int i = 0; i < 4; i++) {
            float iv = 1.f / lacc[qs][i];
            int m = b * T_SEQ + qt * 128 + wave * 32 + qs * 16 + quad * 4 + i;
#pragma unroll
            for (int dt = 0; dt < 4; dt++)
                ab[(size_t)m * CDIM + h * 64 + dt * 16 + l16] = (f16)(o[qs][dt][i] * iv);
        }
    }
}

// ---------------------------------------------------------------------------
// Output GEMM (f16 MFMA): out = ab @ Wout + bias (fp32 out)
// ---------------------------------------------------------------------------
__global__ __launch_bounds__(256) void out_gemm_kernel(
    const f16* __restrict__ Ab, const f16* __restrict__ Wt,
    const float* __restrict__ bias, float* __restrict__ out)
{
    const int m0 = blockIdx.x * 128;
    const int n0 = blockIdx.y * 128;
    GEMM_MAINLOOP(Ab, Wt, m0, n0)

    const int ncol0 = n0 + wn * 64;
    float bia[4];
#pragma unroll
    for (int ni = 0; ni < 4; ni++) bia[ni] = bias[ncol0 + ni * 16 + l16];
#pragma unroll
    for (int mi = 0; mi < 4; mi++) {
#pragma unroll
        for (int i = 0; i < 4; i++) {
            int m = m0 + wm * 64 + mi * 16 + quad * 4 + i;
#pragma unroll
            for (int ni = 0; ni < 4; ni++)
                out[(size_t)m * CDIM + ncol0 + ni * 16 + l16] = acc[mi][ni][i] + bia[ni];
        }
    }
}

// ---------------------------------------------------------------------------
extern "C" void kernel_launch(void* const* d_in, const int* in_sizes, int n_in,
                              void* d_out, int out_size, void* d_ws, size_t ws_size,
                              hipStream_t stream)
{
    const float* x    = (const float*)d_in[0];
    const float* Wqkv = (const float*)d_in[1];
    const float* bqkv = (const float*)d_in[2];
    const float* Wout = (const float*)d_in[3];
    const float* bout = (const float*)d_in[4];
    float* out = (float*)d_out;

    const size_t XSZ  = (size_t)MROWS * CDIM;        // 8,388,608
    const size_t WQSZ = (size_t)3072 * CDIM;         // 3,145,728
    const size_t WOSZ = (size_t)CDIM * CDIM;         // 1,048,576
    const size_t QSZ  = (size_t)BHN * T_SEQ * DHD;   // 8,388,608

    char* p = (char*)d_ws;
    f16* Xf  = (f16*)p; p += XSZ * 2;
    f16* Wqt = (f16*)p; p += WQSZ * 2;
    f16* Wot = (f16*)p; p += WOSZ * 2;
    f16* qf  = (f16*)p; p += QSZ * 2;
    f16* kf  = (f16*)p; p += QSZ * 2;
    f16* vf  = (f16*)p; p += QSZ * 2;
    f16* vtb = (f16*)p; p += QSZ * 2;
    f16* ab  = (f16*)p; p += QSZ * 2;
    float* ctab = (float*)p; p += T_SEQ * 32 * 4;
    float* stab = (float*)p; p += T_SEQ * 32 * 4;
    // total ~110 MB

    rope_tables_kernel<<<256, 256, 0, stream>>>(ctab, stab);
    xcvt_kernel<<<(int)(XSZ / 8 / 256), 256, 0, stream>>>(x, Xf);
    wcvt_kernel<<<dim3(128, 48), 64, 0, stream>>>(Wqkv, Wqt, 3072);
    wcvt_kernel<<<dim3(128, 16), 64, 0, stream>>>(Wout, Wot, 1024);
    qkv_gemm_kernel<<<dim3(64, 24), 256, 0, stream>>>(
        Xf, Wqt, bqkv, ctab, stab, qf, kf, vf);
    vt_kernel<<<dim3(32, BHN), 256, 0, stream>>>(vf, vtb);
    attn_kernel<<<dim3(16, BHN), 256, 0, stream>>>(qf, kf, vtb, ab);
    out_gemm_kernel<<<dim3(64, 8), 256, 0, stream>>>(ab, Wot, bout, out);
}

// Round 3
// 297.449 us; speedup vs baseline: 1.0374x; 1.0094x over previous
//
#include <hip/hip_runtime.h>
#include <math.h>

// Problem constants
#define T_SEQ 2048
#define CDIM  1024
#define NH    16
#define DHD   64
#define BATCH 4
#define MROWS (BATCH * T_SEQ)   // 8192
#define BHN   (BATCH * NH)      // 64

typedef _Float16 f16;
typedef __attribute__((ext_vector_type(8))) _Float16 f16x8;
typedef __attribute__((ext_vector_type(4))) _Float16 f16x4;
typedef __attribute__((ext_vector_type(2))) _Float16 f16x2;
typedef __attribute__((ext_vector_type(2))) __fp16 fp16x2;
typedef __attribute__((ext_vector_type(4))) float f32x4;

__device__ __forceinline__ float fast_exp2(float x) {
#if __has_builtin(__builtin_amdgcn_exp2f)
    return __builtin_amdgcn_exp2f(x);
#else
    return exp2f(x);
#endif
}

// packed f32x2 -> f16x2 convert (v_cvt_pkrtz_f16_f32)
__device__ __forceinline__ f16x2 cvt_pk_f16(float a, float b) {
    fp16x2 r = __builtin_amdgcn_cvt_pkrtz(a, b);
    return __builtin_bit_cast(f16x2, r);
}

// async global->LDS, 16B per lane; LDS dest = wave-uniform base + lane*16
__device__ __forceinline__ void gl_lds16(const f16* g, f16* l) {
    __builtin_amdgcn_global_load_lds(
        (const __attribute__((address_space(1))) void*)(g),
        (__attribute__((address_space(3))) void*)(l),
        16, 0, 0);
}

// ---------------------------------------------------------------------------
// RoPE trig tables (fp64 math)
// ---------------------------------------------------------------------------
__global__ void rope_tables_kernel(float* __restrict__ ctab, float* __restrict__ stab)
{
    int idx = blockIdx.x * 256 + threadIdx.x;   // 0 .. 2048*32-1
    int t = idx >> 5, i = idx & 31;
    double inv = pow(10000.0, -(double)(2 * i) / 64.0);
    double a = (double)t * inv;
    ctab[idx] = (float)cos(a);
    stab[idx] = (float)sin(a);
}

// ---------------------------------------------------------------------------
// X convert: fp32 [8192][1024] -> f16, same layout. 8 elems/thread.
// ---------------------------------------------------------------------------
__global__ __launch_bounds__(256) void xcvt_kernel(
    const float* __restrict__ X, f16* __restrict__ Xf)
{
    int idx = blockIdx.x * 256 + threadIdx.x;   // 8-elem chunk index
    const float4* src = (const float4*)X + (size_t)idx * 2;
    float4 a = src[0], b = src[1];
    f16x8 o;
    o[0] = (f16)a.x; o[1] = (f16)a.y; o[2] = (f16)a.z; o[3] = (f16)a.w;
    o[4] = (f16)b.x; o[5] = (f16)b.y; o[6] = (f16)b.z; o[7] = (f16)b.w;
    *((f16x8*)Xf + idx) = o;
}

// ---------------------------------------------------------------------------
// W transpose+convert: W [K][N] fp32 -> Wt [N][K] f16 (K=1024)
// ---------------------------------------------------------------------------
__global__ __launch_bounds__(64) void wcvt_kernel(
    const float* __restrict__ W, f16* __restrict__ Wt, int N)
{
    int lane = threadIdx.x;
    int k0 = blockIdx.x * 8;
    int n = blockIdx.y * 64 + lane;
    f16x8 o;
#pragma unroll
    for (int j = 0; j < 8; j++) o[j] = (f16)W[(size_t)(k0 + j) * N + n];
    *(f16x8*)(Wt + (size_t)n * CDIM + k0) = o;
}

// ---------------------------------------------------------------------------
// f16 MFMA GEMM mainloop: C[128x128] = A[128xK] B_t[128xK], K=1024
// ---------------------------------------------------------------------------
#define GEMM_MAINLOOP(Aimg, Bimg, M0, N0)                                         \
    __shared__ f16 As[128][32], Bs[128][32];                                      \
    const int tid = threadIdx.x, wave = tid >> 6, lane = tid & 63;                \
    const int l16 = lane & 15, quad = lane >> 4;                                  \
    const int wm = wave >> 1, wn = wave & 1;                                      \
    f32x4 acc[4][4];                                                              \
    _Pragma("unroll") for (int i = 0; i < 4; i++)                                 \
        _Pragma("unroll") for (int j = 0; j < 4; j++)                             \
            acc[i][j] = (f32x4){0.f, 0.f, 0.f, 0.f};                              \
    const f16* sbase = (wave < 2) ? (Aimg) : (Bimg);                              \
    f16* lbase = ((wave < 2) ? &As[0][0] : &Bs[0][0]) + (wave & 1) * 2048;        \
    const size_t srow0 = ((wave < 2) ? (size_t)(M0) : (size_t)(N0)) + (wave & 1) * 64; \
    const int srow = lane >> 2, schunk = (lane & 3) << 3;                         \
    for (int k0 = 0; k0 < CDIM; k0 += 32) {                                       \
        _Pragma("unroll") for (int it = 0; it < 4; it++)                          \
            gl_lds16(sbase + (srow0 + it * 16 + srow) * CDIM + k0 + schunk,       \
                     lbase + it * 512);                                           \
        __syncthreads();                                                          \
        f16x8 fa[4], fb[4];                                                       \
        _Pragma("unroll") for (int mi = 0; mi < 4; mi++)                          \
            fa[mi] = *(const f16x8*)&As[wm * 64 + mi * 16 + l16][quad * 8];       \
        _Pragma("unroll") for (int ni = 0; ni < 4; ni++)                          \
            fb[ni] = *(const f16x8*)&Bs[wn * 64 + ni * 16 + l16][quad * 8];       \
        _Pragma("unroll") for (int mi = 0; mi < 4; mi++)                          \
            _Pragma("unroll") for (int ni = 0; ni < 4; ni++)                      \
                acc[mi][ni] = __builtin_amdgcn_mfma_f32_16x16x32_f16(             \
                    fa[mi], fb[ni], acc[mi][ni], 0, 0, 0);                        \
        __syncthreads();                                                          \
    }

// ---------------------------------------------------------------------------
// QKV GEMM (f16 MFMA), fused bias + RoPE; writes q/k/v f16 in [bh][t][d].
// Q is pre-scaled by (1/8)*log2(e)  -->  attn uses exp2 directly.
// ---------------------------------------------------------------------------
__global__ __launch_bounds__(256) void qkv_gemm_kernel(
    const f16* __restrict__ Xf, const f16* __restrict__ Wt,
    const float* __restrict__ bias,
    const float* __restrict__ ctab, const float* __restrict__ stab,
    f16* __restrict__ qf, f16* __restrict__ kf, f16* __restrict__ vf)
{
    const int m0 = blockIdx.x * 128;
    const int n0 = blockIdx.y * 128;
    GEMM_MAINLOOP(Xf, Wt, m0, n0)

    const int ncol0 = n0 + wn * 64;            // 64-aligned -> one head group
    const int w = ncol0 >> 10;                 // 0=q 1=k 2=v
    const int h = (ncol0 >> 6) & 15;
    const int b = m0 >> 11;
    const int trow0 = (m0 & 2047) + wm * 64 + quad * 4;
    float bia[4];
#pragma unroll
    for (int ni = 0; ni < 4; ni++) bia[ni] = bias[ncol0 + ni * 16 + l16];

    if (w < 2) {
        f16* oq = w ? kf : qf;
        // q scale folds softmax 1/8 AND log2(e) so attn can use v_exp (2^x)
        const float sc = w ? 1.0f : 0.18033688011112042f;
#pragma unroll
        for (int mi = 0; mi < 4; mi++) {
#pragma unroll
            for (int i = 0; i < 4; i++) {
                int t = trow0 + mi * 16 + i;
                size_t rowoff = ((size_t)(b * NH + h) * T_SEQ + t) * DHD;
#pragma unroll
                for (int np = 0; np < 2; np++) {
                    int d = np * 16 + l16;             // 0..31
                    float v0 = acc[mi][np][i] + bia[np];
                    float v1 = acc[mi][np + 2][i] + bia[np + 2];
                    float c = ctab[(t << 5) + d];
                    float s = stab[(t << 5) + d];
                    oq[rowoff + d]      = (f16)((v0 * c - v1 * s) * sc);
                    oq[rowoff + d + 32] = (f16)((v1 * c + v0 * s) * sc);
                }
            }
        }
    } else {
#pragma unroll
        for (int mi = 0; mi < 4; mi++) {
#pragma unroll
            for (int i = 0; i < 4; i++) {
                int t = trow0 + mi * 16 + i;
                size_t rowoff = ((size_t)(b * NH + h) * T_SEQ + t) * DHD;
#pragma unroll
                for (int ni = 0; ni < 4; ni++)
                    vf[rowoff + ni * 16 + l16] = (f16)(acc[mi][ni][i] + bia[ni]);
            }
        }
    }
}

// ---------------------------------------------------------------------------
// V transpose: vf [bh][t][d] f16 -> vt [bh][d][t] f16
// ---------------------------------------------------------------------------
__global__ __launch_bounds__(256) void vt_kernel(
    const f16* __restrict__ vf, f16* __restrict__ vt)
{
    __shared__ f16 Ls[64][72];
    const int tid = threadIdx.x;
    const int tb = blockIdx.x;   // 0..31
    const int bh = blockIdx.y;   // 0..63
#pragma unroll
    for (int p = 0; p < 2; p++) {
        int idx = tid + p * 256;
        int r = idx >> 3, c8 = (idx & 7) << 3;
        *(f16x8*)&Ls[r][c8] =
            *(const f16x8*)(vf + ((size_t)bh * T_SEQ + tb * 64 + r) * DHD + c8);
    }
    __syncthreads();
#pragma unroll
    for (int p = 0; p < 2; p++) {
        int idx = tid + p * 256;
        int d = idx >> 3, t8 = (idx & 7) << 3;
        f16x8 o;
#pragma unroll
        for (int j = 0; j < 8; j++) o[j] = Ls[t8 + j][d];
        *(f16x8*)(vt + ((size_t)bh * DHD + d) * T_SEQ + (size_t)tb * 64 + t8) = o;
    }
}

// ---------------------------------------------------------------------------
// f16 MFMA flash attention v3:
//  - 128-query blocks, 4 waves x 32 queries; grid 16x64 = 1024 blocks
//    = 4 blocks/CU (LDS = 40960B exactly)
//  - K/V: chunk-XOR swizzle (conflict-free b128 reads + staging writes)
//  - P: row-rotated dword layout: phys_dword = (log_dword + (row&14)) & 15.
//    b64 writes and 2x b64 reads are both 16-distinct-bank-pair -> CF.
//    (chunk-XOR can NOT be conflict-free here: 64B rows only expose 8
//    bank-pair slots at 8B granularity; rotation exposes all 16.)
//  - exp2-direct softmax, cvt_pkrtz packing, l via MFMA(P, ones)
//  - XCD-chunked block swizzle (FETCH 142->27MB measured)
// ---------------------------------------------------------------------------
__global__ __launch_bounds__(256, 4) void attn_kernel(
    const f16* __restrict__ qf, const f16* __restrict__ kf,
    const f16* __restrict__ vt, f16* __restrict__ ab)
{
    __shared__ f16 Kb[2][64][64];     // [buf][key][d]   16384B, chunk-swizzled
    __shared__ f16 Vb[2][64][64];     // [buf][d][key]   16384B, chunk-swizzled
    __shared__ f16 Pb[4][32][32];     // per-wave [query][key%32] 8192B, rotated
    // total 40960B -> exactly 4 blocks/CU

    const int tid  = threadIdx.x;
    const int wave = tid >> 6, lane = tid & 63;
    const int l16  = lane & 15, quad = lane >> 4;

    // XCD-chunked swizzle: flat id -> (qt, bh) so XCD x holds bh in [8x, 8x+8)
    const int flat = blockIdx.x + (blockIdx.y << 4);     // 0..1023
    const int swz  = (flat & 7) * 128 + (flat >> 3);     // bijective (1024%8==0)
    const int qt = swz & 15;                             // 0..15
    const int bh = swz >> 4;                             // 0..63
    const int q0 = qt * 128 + wave * 32;                 // wave's query base

    const f16* kbase = kf + (size_t)bh * T_SEQ * DHD;
    const f16* vbase = vt + (size_t)bh * DHD * T_SEQ;

    // Q B-frags [qsub][ks]: B[n=query=l16][k=d=quad*8+j]
    f16x8 qfr[2][2];
#pragma unroll
    for (int qs = 0; qs < 2; qs++) {
        const f16* qrow = qf + ((size_t)bh * T_SEQ + q0 + qs * 16 + l16) * DHD;
        qfr[qs][0] = *(const f16x8*)(qrow + quad * 8);
        qfr[qs][1] = *(const f16x8*)(qrow + 32 + quad * 8);
    }

    f32x4 o[2][4];      // [qsub][dt], C-layout row=query col=d
    f32x4 lacc[2];      // l partials, same row layout as o
#pragma unroll
    for (int qs = 0; qs < 2; qs++) {
        lacc[qs] = (f32x4){0.f, 0.f, 0.f, 0.f};
#pragma unroll
        for (int dt = 0; dt < 4; dt++) o[qs][dt] = (f32x4){0.f, 0.f, 0.f, 0.f};
    }
    f16x8 ones;
#pragma unroll
    for (int j = 0; j < 8; j++) ones[j] = (f16)1.0f;

    // staging map: 256 threads x 2 rounds x b128 = 8KB per array per tile
    const int srow = tid >> 3;                       // 0..31
    const int scw  = tid & 7;                        // chunk 0..7
    const int scol = scw << 3;                       // global f16 col
    const int swzc = (scw ^ (srow & 7)) << 3;        // swizzled LDS f16 col

    // P layout: row-rotation (in dwords) for bank-conflict-free b64 access
    const int prot = l16 & 14;                       // rotation, dwords (even)

    f16x8 kreg[2], vreg[2];
#pragma unroll
    for (int r = 0; r < 2; r++) {
        kreg[r] = *(const f16x8*)(kbase + (size_t)(srow + r * 32) * DHD + scol);
        vreg[r] = *(const f16x8*)(vbase + (size_t)(srow + r * 32) * T_SEQ + scol);
    }
#pragma unroll
    for (int r = 0; r < 2; r++) {
        *(f16x8*)&Kb[0][srow + r * 32][swzc] = kreg[r];
        *(f16x8*)&Vb[0][srow + r * 32][swzc] = vreg[r];
    }
    __syncthreads();

    for (int kt = 0; kt < 32; kt++) {
        const int buf = kt & 1;
        if (kt < 31) {   // prefetch next tile into registers (no wait)
#pragma unroll
            for (int r = 0; r < 2; r++) {
                kreg[r] = *(const f16x8*)(kbase + (size_t)((kt + 1) * 64 + srow + r * 32) * DHD + scol);
                vreg[r] = *(const f16x8*)(vbase + (size_t)(srow + r * 32) * T_SEQ + (kt + 1) * 64 + scol);
            }
        }

#pragma unroll
        for (int half = 0; half < 2; half++) {
            // ---- S^T for 32 keys x 32 queries ----
            f32x4 sc[2][2];   // [keysub][qsub]
#pragma unroll
            for (int k2 = 0; k2 < 2; k2++)
#pragma unroll
                for (int qs = 0; qs < 2; qs++) sc[k2][qs] = (f32x4){0.f, 0.f, 0.f, 0.f};
#pragma unroll
            for (int k2 = 0; k2 < 2; k2++) {
                const int keyt = half * 2 + k2;
#pragma unroll
                for (int ks = 0; ks < 2; ks++) {
                    const int kc = ((ks * 4 + quad) ^ (l16 & 7)) << 3;
                    f16x8 kfr = *(const f16x8*)&Kb[buf][keyt * 16 + l16][kc];
#pragma unroll
                    for (int qs = 0; qs < 2; qs++)
                        sc[k2][qs] = __builtin_amdgcn_mfma_f32_16x16x32_f16(
                            kfr, qfr[qs][ks], sc[k2][qs], 0, 0, 0);
                }
            }
            // ---- exp2 (log2e pre-folded), pack P via cvt_pkrtz ----
            // write: logical dword = 8*k2 + 2*quad (keys k2*16+quad*4..+3),
            // phys dword = (log + prot) & 15 -> conflict-free b64 store
#pragma unroll
            for (int k2 = 0; k2 < 2; k2++) {
#pragma unroll
                for (int qs = 0; qs < 2; qs++) {
                    f16x2 pa = cvt_pk_f16(
                        fast_exp2(sc[k2][qs][0]), fast_exp2(sc[k2][qs][1]));
                    f16x2 pb = cvt_pk_f16(
                        fast_exp2(sc[k2][qs][2]), fast_exp2(sc[k2][qs][3]));
                    f16x4 pv;
                    ((f16x2*)&pv)[0] = pa;
                    ((f16x2*)&pv)[1] = pb;
                    const int pc = (((k2 << 3) + (quad << 1) + prot) & 15) << 1;
                    *(f16x4*)&Pb[wave][qs * 16 + l16][pc] = pv;
                }
            }
            // ---- P frags (2x b64, same rotation); l += P*ones; PV ----
            const int pr0 = (((quad << 2)     + prot) & 15) << 1;
            const int pr1 = (((quad << 2) + 2 + prot) & 15) << 1;
            f16x8 pfr[2];
#pragma unroll
            for (int qs = 0; qs < 2; qs++) {
                f16x4 plo = *(const f16x4*)&Pb[wave][qs * 16 + l16][pr0];
                f16x4 phi = *(const f16x4*)&Pb[wave][qs * 16 + l16][pr1];
                f16x8 pf;
                pf[0] = plo[0]; pf[1] = plo[1]; pf[2] = plo[2]; pf[3] = plo[3];
                pf[4] = phi[0]; pf[5] = phi[1]; pf[6] = phi[2]; pf[7] = phi[3];
                pfr[qs] = pf;
                lacc[qs] = __builtin_amdgcn_mfma_f32_16x16x32_f16(
                    pfr[qs], ones, lacc[qs], 0, 0, 0);
            }
#pragma unroll
            for (int dt = 0; dt < 4; dt++) {
                const int vc = ((half * 4 + quad) ^ (l16 & 7)) << 3;
                f16x8 vfr = *(const f16x8*)&Vb[buf][dt * 16 + l16][vc];
#pragma unroll
                for (int qs = 0; qs < 2; qs++)
                    o[qs][dt] = __builtin_amdgcn_mfma_f32_16x16x32_f16(
                        pfr[qs], vfr, o[qs][dt], 0, 0, 0);
            }
        }

        if (kt < 31) {   // write prefetched tile into the other buffer
#pragma unroll
            for (int r = 0; r < 2; r++) {
                *(f16x8*)&Kb[buf ^ 1][srow + r * 32][swzc] = kreg[r];
                *(f16x8*)&Vb[buf ^ 1][srow + r * 32][swzc] = vreg[r];
            }
        }
        __syncthreads();
    }

    // ---- epilogue: normalize by lane-local 1/l, write ab[q][h*64+d] ----
    const int b = bh >> 4, h = bh & 15;
#pragma unroll
    for (int qs = 0; qs < 2; qs++) {
#pragma unroll
        for (int i = 0; i < 4; i++) {
            float iv = 1.f / lacc[qs][i];
            int m = b * T_SEQ + qt * 128 + wave * 32 + qs * 16 + quad * 4 + i;
#pragma unroll
            for (int dt = 0; dt < 4; dt++)
                ab[(size_t)m * CDIM + h * 64 + dt * 16 + l16] = (f16)(o[qs][dt][i] * iv);
        }
    }
}

// ---------------------------------------------------------------------------
// Output GEMM (f16 MFMA): out = ab @ Wout + bias (fp32 out)
// ---------------------------------------------------------------------------
__global__ __launch_bounds__(256) void out_gemm_kernel(
    const f16* __restrict__ Ab, const f16* __restrict__ Wt,
    const float* __restrict__ bias, float* __restrict__ out)
{
    const int m0 = blockIdx.x * 128;
    const int n0 = blockIdx.y * 128;
    GEMM_MAINLOOP(Ab, Wt, m0, n0)

    const int ncol0 = n0 + wn * 64;
    float bia[4];
#pragma unroll
    for (int ni = 0; ni < 4; ni++) bia[ni] = bias[ncol0 + ni * 16 + l16];
#pragma unroll
    for (int mi = 0; mi < 4; mi++) {
#pragma unroll
        for (int i = 0; i < 4; i++) {
            int m = m0 + wm * 64 + mi * 16 + quad * 4 + i;
#pragma unroll
            for (int ni = 0; ni < 4; ni++)
                out[(size_t)m * CDIM + ncol0 + ni * 16 + l16] = acc[mi][ni][i] + bia[ni];
        }
    }
}

// ---------------------------------------------------------------------------
extern "C" void kernel_launch(void* const* d_in, const int* in_sizes, int n_in,
                              void* d_out, int out_size, void* d_ws, size_t ws_size,
                              hipStream_t stream)
{
    const float* x    = (const float*)d_in[0];
    const float* Wqkv = (const float*)d_in[1];
    const float* bqkv = (const float*)d_in[2];
    const float* Wout = (const float*)d_in[3];
    const float* bout = (const float*)d_in[4];
    float* out = (float*)d_out;

    const size_t XSZ  = (size_t)MROWS * CDIM;        // 8,388,608
    const size_t WQSZ = (size_t)3072 * CDIM;         // 3,145,728
    const size_t WOSZ = (size_t)CDIM * CDIM;         // 1,048,576
    const size_t QSZ  = (size_t)BHN * T_SEQ * DHD;   // 8,388,608

    char* p = (char*)d_ws;
    f16* Xf  = (f16*)p; p += XSZ * 2;
    f16* Wqt = (f16*)p; p += WQSZ * 2;
    f16* Wot = (f16*)p; p += WOSZ * 2;
    f16* qf  = (f16*)p; p += QSZ * 2;
    f16* kf  = (f16*)p; p += QSZ * 2;
    f16* vf  = (f16*)p; p += QSZ * 2;
    f16* vtb = (f16*)p; p += QSZ * 2;
    f16* ab  = (f16*)p; p += QSZ * 2;
    float* ctab = (float*)p; p += T_SEQ * 32 * 4;
    float* stab = (float*)p; p += T_SEQ * 32 * 4;
    // total ~110 MB

    rope_tables_kernel<<<256, 256, 0, stream>>>(ctab, stab);
    xcvt_kernel<<<(int)(XSZ / 8 / 256), 256, 0, stream>>>(x, Xf);
    wcvt_kernel<<<dim3(128, 48), 64, 0, stream>>>(Wqkv, Wqt, 3072);
    wcvt_kernel<<<dim3(128, 16), 64, 0, stream>>>(Wout, Wot, 1024);
    qkv_gemm_kernel<<<dim3(64, 24), 256, 0, stream>>>(
        Xf, Wqt, bqkv, ctab, stab, qf, kf, vf);
    vt_kernel<<<dim3(32, BHN), 256, 0, stream>>>(vf, vtb);
    attn_kernel<<<dim3(16, BHN), 256, 0, stream>>>(qf, kf, vtb, ab);
    out_gemm_kernel<<<dim3(64, 8), 256, 0, stream>>>(ab, Wot, bout, out);
}

// Round 4
// 294.651 us; speedup vs baseline: 1.0473x; 1.0095x over previous
//
#include <hip/hip_runtime.h>
#include <math.h>

// Problem constants
#define T_SEQ 2048
#define CDIM  1024
#define NH    16
#define DHD   64
#define BATCH 4
#define MROWS (BATCH * T_SEQ)   // 8192
#define BHN   (BATCH * NH)      // 64

typedef _Float16 f16;
typedef __attribute__((ext_vector_type(8))) _Float16 f16x8;
typedef __attribute__((ext_vector_type(4))) _Float16 f16x4;
typedef __attribute__((ext_vector_type(2))) _Float16 f16x2;
typedef __attribute__((ext_vector_type(2))) __fp16 fp16x2;
typedef __attribute__((ext_vector_type(4))) float f32x4;

__device__ __forceinline__ float fast_exp2(float x) {
#if __has_builtin(__builtin_amdgcn_exp2f)
    return __builtin_amdgcn_exp2f(x);
#else
    return exp2f(x);
#endif
}

__device__ __forceinline__ float fast_rcp(float x) {
#if __has_builtin(__builtin_amdgcn_rcpf)
    return __builtin_amdgcn_rcpf(x);
#else
    return 1.0f / x;
#endif
}

// packed f32x2 -> f16x2 convert (v_cvt_pkrtz_f16_f32)
__device__ __forceinline__ f16x2 cvt_pk_f16(float a, float b) {
    fp16x2 r = __builtin_amdgcn_cvt_pkrtz(a, b);
    return __builtin_bit_cast(f16x2, r);
}

// async global->LDS, 16B per lane; LDS dest = wave-uniform base + lane*16
__device__ __forceinline__ void gl_lds16(const f16* g, f16* l) {
    __builtin_amdgcn_global_load_lds(
        (const __attribute__((address_space(1))) void*)(g),
        (__attribute__((address_space(3))) void*)(l),
        16, 0, 0);
}

// ---------------------------------------------------------------------------
// RoPE trig tables (fp64 math)
// ---------------------------------------------------------------------------
__global__ void rope_tables_kernel(float* __restrict__ ctab, float* __restrict__ stab)
{
    int idx = blockIdx.x * 256 + threadIdx.x;   // 0 .. 2048*32-1
    int t = idx >> 5, i = idx & 31;
    double inv = pow(10000.0, -(double)(2 * i) / 64.0);
    double a = (double)t * inv;
    ctab[idx] = (float)cos(a);
    stab[idx] = (float)sin(a);
}

// ---------------------------------------------------------------------------
// X convert: fp32 [8192][1024] -> f16, same layout. 8 elems/thread.
// ---------------------------------------------------------------------------
__global__ __launch_bounds__(256) void xcvt_kernel(
    const float* __restrict__ X, f16* __restrict__ Xf)
{
    int idx = blockIdx.x * 256 + threadIdx.x;   // 8-elem chunk index
    const float4* src = (const float4*)X + (size_t)idx * 2;
    float4 a = src[0], b = src[1];
    f16x8 o;
    o[0] = (f16)a.x; o[1] = (f16)a.y; o[2] = (f16)a.z; o[3] = (f16)a.w;
    o[4] = (f16)b.x; o[5] = (f16)b.y; o[6] = (f16)b.z; o[7] = (f16)b.w;
    *((f16x8*)Xf + idx) = o;
}

// ---------------------------------------------------------------------------
// W transpose+convert (both weights in one launch):
//   y <  48 : Wqkv [1024][3072] -> Wqt [3072][1024]
//   y >= 48 : Wout [1024][1024] -> Wot [1024][1024]
// ---------------------------------------------------------------------------
__global__ __launch_bounds__(64) void wcvt_kernel(
    const float* __restrict__ Wq, const float* __restrict__ Wo,
    f16* __restrict__ Wqt, f16* __restrict__ Wot)
{
    int lane = threadIdx.x;
    int k0 = blockIdx.x * 8;
    int ny = blockIdx.y;
    const float* W;
    f16* Wt;
    int N, n;
    if (ny < 48) { W = Wq; Wt = Wqt; N = 3072; n = ny * 64 + lane; }
    else         { W = Wo; Wt = Wot; N = 1024; n = (ny - 48) * 64 + lane; }
    f16x8 o;
#pragma unroll
    for (int j = 0; j < 8; j++) o[j] = (f16)W[(size_t)(k0 + j) * N + n];
    *(f16x8*)(Wt + (size_t)n * CDIM + k0) = o;
}

// ---------------------------------------------------------------------------
// f16 MFMA GEMM mainloop: C[128x128] = A[128xK] B_t[128xK], K=1024
// ---------------------------------------------------------------------------
#define GEMM_MAINLOOP(Aimg, Bimg, M0, N0)                                         \
    __shared__ f16 As[128][32], Bs[128][32];                                      \
    const int tid = threadIdx.x, wave = tid >> 6, lane = tid & 63;                \
    const int l16 = lane & 15, quad = lane >> 4;                                  \
    const int wm = wave >> 1, wn = wave & 1;                                      \
    f32x4 acc[4][4];                                                              \
    _Pragma("unroll") for (int i = 0; i < 4; i++)                                 \
        _Pragma("unroll") for (int j = 0; j < 4; j++)                             \
            acc[i][j] = (f32x4){0.f, 0.f, 0.f, 0.f};                              \
    const f16* sbase = (wave < 2) ? (Aimg) : (Bimg);                              \
    f16* lbase = ((wave < 2) ? &As[0][0] : &Bs[0][0]) + (wave & 1) * 2048;        \
    const size_t srow0 = ((wave < 2) ? (size_t)(M0) : (size_t)(N0)) + (wave & 1) * 64; \
    const int srow = lane >> 2, schunk = (lane & 3) << 3;                         \
    for (int k0 = 0; k0 < CDIM; k0 += 32) {                                       \
        _Pragma("unroll") for (int it = 0; it < 4; it++)                          \
            gl_lds16(sbase + (srow0 + it * 16 + srow) * CDIM + k0 + schunk,       \
                     lbase + it * 512);                                           \
        __syncthreads();                                                          \
        f16x8 fa[4], fb[4];                                                       \
        _Pragma("unroll") for (int mi = 0; mi < 4; mi++)                          \
            fa[mi] = *(const f16x8*)&As[wm * 64 + mi * 16 + l16][quad * 8];       \
        _Pragma("unroll") for (int ni = 0; ni < 4; ni++)                          \
            fb[ni] = *(const f16x8*)&Bs[wn * 64 + ni * 16 + l16][quad * 8];       \
        _Pragma("unroll") for (int mi = 0; mi < 4; mi++)                          \
            _Pragma("unroll") for (int ni = 0; ni < 4; ni++)                      \
                acc[mi][ni] = __builtin_amdgcn_mfma_f32_16x16x32_f16(             \
                    fa[mi], fb[ni], acc[mi][ni], 0, 0, 0);                        \
        __syncthreads();                                                          \
    }

// ---------------------------------------------------------------------------
// QKV GEMM (f16 MFMA), fused bias + RoPE; writes q/k in [bh][t][d], and V
// DIRECTLY TRANSPOSED into vt [bh][d][t] (vt_kernel eliminated).
// Q is pre-scaled by (1/8)*log2(e)  -->  attn uses exp2 directly.
// ---------------------------------------------------------------------------
__global__ __launch_bounds__(256) void qkv_gemm_kernel(
    const f16* __restrict__ Xf, const f16* __restrict__ Wt,
    const float* __restrict__ bias,
    const float* __restrict__ ctab, const float* __restrict__ stab,
    f16* __restrict__ qf, f16* __restrict__ kf, f16* __restrict__ vtb)
{
    const int m0 = blockIdx.x * 128;
    const int n0 = blockIdx.y * 128;
    GEMM_MAINLOOP(Xf, Wt, m0, n0)

    const int ncol0 = n0 + wn * 64;            // 64-aligned -> one head group
    const int w = ncol0 >> 10;                 // 0=q 1=k 2=v
    const int h = (ncol0 >> 6) & 15;
    const int b = m0 >> 11;
    const int trow0 = (m0 & 2047) + wm * 64 + quad * 4;
    float bia[4];
#pragma unroll
    for (int ni = 0; ni < 4; ni++) bia[ni] = bias[ncol0 + ni * 16 + l16];

    if (w < 2) {
        f16* oq = w ? kf : qf;
        // q scale folds softmax 1/8 AND log2(e) so attn can use v_exp (2^x)
        const float sc = w ? 1.0f : 0.18033688011112042f;
#pragma unroll
        for (int mi = 0; mi < 4; mi++) {
#pragma unroll
            for (int i = 0; i < 4; i++) {
                int t = trow0 + mi * 16 + i;
                size_t rowoff = ((size_t)(b * NH + h) * T_SEQ + t) * DHD;
#pragma unroll
                for (int np = 0; np < 2; np++) {
                    int d = np * 16 + l16;             // 0..31
                    float v0 = acc[mi][np][i] + bia[np];
                    float v1 = acc[mi][np + 2][i] + bia[np + 2];
                    float c = ctab[(t << 5) + d];
                    float s = stab[(t << 5) + d];
                    oq[rowoff + d]      = (f16)((v0 * c - v1 * s) * sc);
                    oq[rowoff + d + 32] = (f16)((v1 * c + v0 * s) * sc);
                }
            }
        }
    } else {
        // V: store transposed. acc[mi][ni][0..3] are 4 consecutive t for one
        // d -> one f16x4 store per (mi,ni) into vt[bh][d][t].
#pragma unroll
        for (int mi = 0; mi < 4; mi++) {
            const int tb = trow0 + mi * 16;    // includes quad*4; 4-aligned
#pragma unroll
            for (int ni = 0; ni < 4; ni++) {
                const int d = ni * 16 + l16;
                f16x4 pv;
#pragma unroll
                for (int i = 0; i < 4; i++) pv[i] = (f16)(acc[mi][ni][i] + bia[ni]);
                *(f16x4*)(vtb + ((size_t)(b * NH + h) * DHD + d) * T_SEQ + tb) = pv;
            }
        }
    }
}

// ---------------------------------------------------------------------------
// f16 MFMA flash attention v4:
//  - 128-query blocks, 4 waves x 32 queries; grid 16x64 = 1024 blocks
//    = 4 blocks/CU (LDS = 40960B exactly)
//  - K/V: chunk-XOR swizzle (conflict-free b128 reads + staging writes)
//  - P: row-rotated dword layout (conflict-free b64 writes + reads)
//  - exp2-direct softmax, cvt_pkrtz packing, l via MFMA(P, ones)
//  - s_setprio(1) around MFMA clusters; incremental prefetch pointers
//  - XCD-chunked block swizzle (FETCH 142->25MB measured)
// ---------------------------------------------------------------------------
__global__ __launch_bounds__(256, 4) void attn_kernel(
    const f16* __restrict__ qf, const f16* __restrict__ kf,
    const f16* __restrict__ vt, f16* __restrict__ ab)
{
    __shared__ f16 Kb[2][64][64];     // [buf][key][d]   16384B, chunk-swizzled
    __shared__ f16 Vb[2][64][64];     // [buf][d][key]   16384B, chunk-swizzled
    __shared__ f16 Pb[4][32][32];     // per-wave [query][key%32] 8192B, rotated
    // total 40960B -> exactly 4 blocks/CU

    const int tid  = threadIdx.x;
    const int wave = tid >> 6, lane = tid & 63;
    const int l16  = lane & 15, quad = lane >> 4;

    // XCD-chunked swizzle: flat id -> (qt, bh) so XCD x holds bh in [8x, 8x+8)
    const int flat = blockIdx.x + (blockIdx.y << 4);     // 0..1023
    const int swz  = (flat & 7) * 128 + (flat >> 3);     // bijective (1024%8==0)
    const int qt = swz & 15;                             // 0..15
    const int bh = swz >> 4;                             // 0..63
    const int q0 = qt * 128 + wave * 32;                 // wave's query base

    const f16* kbase = kf + (size_t)bh * T_SEQ * DHD;
    const f16* vbase = vt + (size_t)bh * DHD * T_SEQ;

    // Q B-frags [qsub][ks]: B[n=query=l16][k=d=quad*8+j]
    f16x8 qfr[2][2];
#pragma unroll
    for (int qs = 0; qs < 2; qs++) {
        const f16* qrow = qf + ((size_t)bh * T_SEQ + q0 + qs * 16 + l16) * DHD;
        qfr[qs][0] = *(const f16x8*)(qrow + quad * 8);
        qfr[qs][1] = *(const f16x8*)(qrow + 32 + quad * 8);
    }

    f32x4 o[2][4];      // [qsub][dt], C-layout row=query col=d
    f32x4 lacc[2];      // l partials, same row layout as o
#pragma unroll
    for (int qs = 0; qs < 2; qs++) {
        lacc[qs] = (f32x4){0.f, 0.f, 0.f, 0.f};
#pragma unroll
        for (int dt = 0; dt < 4; dt++) o[qs][dt] = (f32x4){0.f, 0.f, 0.f, 0.f};
    }
    f16x8 ones;
#pragma unroll
    for (int j = 0; j < 8; j++) ones[j] = (f16)1.0f;

    // staging map: 256 threads x 2 rounds x b128 = 8KB per array per tile
    const int srow = tid >> 3;                       // 0..31
    const int scw  = tid & 7;                        // chunk 0..7
    const int scol = scw << 3;                       // global f16 col
    const int swzc = (scw ^ (srow & 7)) << 3;        // swizzled LDS f16 col

    // P layout: row-rotation (in dwords) for bank-conflict-free b64 access
    const int prot = l16 & 14;                       // rotation, dwords (even)

    // per-thread staging pointers (incremented, not recomputed)
    const f16* kp = kbase + (size_t)srow * DHD + scol;
    const f16* vp = vbase + (size_t)srow * T_SEQ + scol;

    f16x8 kreg[2], vreg[2];
#pragma unroll
    for (int r = 0; r < 2; r++) {
        kreg[r] = *(const f16x8*)(kp + (size_t)(r * 32) * DHD);
        vreg[r] = *(const f16x8*)(vp + (size_t)(r * 32) * T_SEQ);
    }
#pragma unroll
    for (int r = 0; r < 2; r++) {
        *(f16x8*)&Kb[0][srow + r * 32][swzc] = kreg[r];
        *(f16x8*)&Vb[0][srow + r * 32][swzc] = vreg[r];
    }
    const f16* kq = kp + 64 * DHD;   // next-tile pointers
    const f16* vq = vp + 64;
    __syncthreads();

    for (int kt = 0; kt < 32; kt++) {
        const int buf = kt & 1;
        if (kt < 31) {   // prefetch next tile into registers (no wait)
#pragma unroll
            for (int r = 0; r < 2; r++) {
                kreg[r] = *(const f16x8*)(kq + (size_t)(r * 32) * DHD);
                vreg[r] = *(const f16x8*)(vq + (size_t)(r * 32) * T_SEQ);
            }
            kq += 64 * DHD;
            vq += 64;
        }

#pragma unroll
        for (int half = 0; half < 2; half++) {
            // ---- S^T for 32 keys x 32 queries ----
            f32x4 sc[2][2];   // [keysub][qsub]
#pragma unroll
            for (int k2 = 0; k2 < 2; k2++)
#pragma unroll
                for (int qs = 0; qs < 2; qs++) sc[k2][qs] = (f32x4){0.f, 0.f, 0.f, 0.f};
            __builtin_amdgcn_s_setprio(1);
#pragma unroll
            for (int k2 = 0; k2 < 2; k2++) {
                const int keyt = half * 2 + k2;
#pragma unroll
                for (int ks = 0; ks < 2; ks++) {
                    const int kc = ((ks * 4 + quad) ^ (l16 & 7)) << 3;
                    f16x8 kfr = *(const f16x8*)&Kb[buf][keyt * 16 + l16][kc];
#pragma unroll
                    for (int qs = 0; qs < 2; qs++)
                        sc[k2][qs] = __builtin_amdgcn_mfma_f32_16x16x32_f16(
                            kfr, qfr[qs][ks], sc[k2][qs], 0, 0, 0);
                }
            }
            __builtin_amdgcn_s_setprio(0);
            // ---- exp2 (log2e pre-folded), pack P via cvt_pkrtz ----
            // write: logical dword = 8*k2 + 2*quad (keys k2*16+quad*4..+3),
            // phys dword = (log + prot) & 15 -> conflict-free b64 store
#pragma unroll
            for (int k2 = 0; k2 < 2; k2++) {
#pragma unroll
                for (int qs = 0; qs < 2; qs++) {
                    f16x2 pa = cvt_pk_f16(
                        fast_exp2(sc[k2][qs][0]), fast_exp2(sc[k2][qs][1]));
                    f16x2 pb = cvt_pk_f16(
                        fast_exp2(sc[k2][qs][2]), fast_exp2(sc[k2][qs][3]));
                    f16x4 pv;
                    ((f16x2*)&pv)[0] = pa;
                    ((f16x2*)&pv)[1] = pb;
                    const int pc = (((k2 << 3) + (quad << 1) + prot) & 15) << 1;
                    *(f16x4*)&Pb[wave][qs * 16 + l16][pc] = pv;
                }
            }
            // ---- P frags (2x b64, same rotation); l += P*ones; PV ----
            const int pr0 = (((quad << 2)     + prot) & 15) << 1;
            const int pr1 = (((quad << 2) + 2 + prot) & 15) << 1;
            f16x8 pfr[2];
#pragma unroll
            for (int qs = 0; qs < 2; qs++) {
                f16x4 plo = *(const f16x4*)&Pb[wave][qs * 16 + l16][pr0];
                f16x4 phi = *(const f16x4*)&Pb[wave][qs * 16 + l16][pr1];
                f16x8 pf;
                pf[0] = plo[0]; pf[1] = plo[1]; pf[2] = plo[2]; pf[3] = plo[3];
                pf[4] = phi[0]; pf[5] = phi[1]; pf[6] = phi[2]; pf[7] = phi[3];
                pfr[qs] = pf;
            }
            __builtin_amdgcn_s_setprio(1);
#pragma unroll
            for (int qs = 0; qs < 2; qs++)
                lacc[qs] = __builtin_amdgcn_mfma_f32_16x16x32_f16(
                    pfr[qs], ones, lacc[qs], 0, 0, 0);
#pragma unroll
            for (int dt = 0; dt < 4; dt++) {
                const int vc = ((half * 4 + quad) ^ (l16 & 7)) << 3;
                f16x8 vfr = *(const f16x8*)&Vb[buf][dt * 16 + l16][vc];
#pragma unroll
                for (int qs = 0; qs < 2; qs++)
                    o[qs][dt] = __builtin_amdgcn_mfma_f32_16x16x32_f16(
                        pfr[qs], vfr, o[qs][dt], 0, 0, 0);
            }
            __builtin_amdgcn_s_setprio(0);
        }

        if (kt < 31) {   // write prefetched tile into the other buffer
#pragma unroll
            for (int r = 0; r < 2; r++) {
                *(f16x8*)&Kb[buf ^ 1][srow + r * 32][swzc] = kreg[r];
                *(f16x8*)&Vb[buf ^ 1][srow + r * 32][swzc] = vreg[r];
            }
        }
        __syncthreads();
    }

    // ---- epilogue: normalize by lane-local 1/l, write ab[q][h*64+d] ----
    const int b = bh >> 4, h = bh & 15;
#pragma unroll
    for (int qs = 0; qs < 2; qs++) {
#pragma unroll
        for (int i = 0; i < 4; i++) {
            float iv = fast_rcp(lacc[qs][i]);
            int m = b * T_SEQ + qt * 128 + wave * 32 + qs * 16 + quad * 4 + i;
#pragma unroll
            for (int dt = 0; dt < 4; dt++)
                ab[(size_t)m * CDIM + h * 64 + dt * 16 + l16] = (f16)(o[qs][dt][i] * iv);
        }
    }
}

// ---------------------------------------------------------------------------
// Output GEMM (f16 MFMA): out = ab @ Wout + bias (fp32 out)
// ---------------------------------------------------------------------------
__global__ __launch_bounds__(256) void out_gemm_kernel(
    const f16* __restrict__ Ab, const f16* __restrict__ Wt,
    const float* __restrict__ bias, float* __restrict__ out)
{
    const int m0 = blockIdx.x * 128;
    const int n0 = blockIdx.y * 128;
    GEMM_MAINLOOP(Ab, Wt, m0, n0)

    const int ncol0 = n0 + wn * 64;
    float bia[4];
#pragma unroll
    for (int ni = 0; ni < 4; ni++) bia[ni] = bias[ncol0 + ni * 16 + l16];
#pragma unroll
    for (int mi = 0; mi < 4; mi++) {
#pragma unroll
        for (int i = 0; i < 4; i++) {
            int m = m0 + wm * 64 + mi * 16 + quad * 4 + i;
#pragma unroll
            for (int ni = 0; ni < 4; ni++)
                out[(size_t)m * CDIM + ncol0 + ni * 16 + l16] = acc[mi][ni][i] + bia[ni];
        }
    }
}

// ---------------------------------------------------------------------------
extern "C" void kernel_launch(void* const* d_in, const int* in_sizes, int n_in,
                              void* d_out, int out_size, void* d_ws, size_t ws_size,
                              hipStream_t stream)
{
    const float* x    = (const float*)d_in[0];
    const float* Wqkv = (const float*)d_in[1];
    const float* bqkv = (const float*)d_in[2];
    const float* Wout = (const float*)d_in[3];
    const float* bout = (const float*)d_in[4];
    float* out = (float*)d_out;

    const size_t XSZ  = (size_t)MROWS * CDIM;        // 8,388,608
    const size_t WQSZ = (size_t)3072 * CDIM;         // 3,145,728
    const size_t WOSZ = (size_t)CDIM * CDIM;         // 1,048,576
    const size_t QSZ  = (size_t)BHN * T_SEQ * DHD;   // 8,388,608

    char* p = (char*)d_ws;
    f16* Xf  = (f16*)p; p += XSZ * 2;
    f16* Wqt = (f16*)p; p += WQSZ * 2;
    f16* Wot = (f16*)p; p += WOSZ * 2;
    f16* qf  = (f16*)p; p += QSZ * 2;
    f16* kf  = (f16*)p; p += QSZ * 2;
    f16* vtb = (f16*)p; p += QSZ * 2;
    f16* ab  = (f16*)p; p += QSZ * 2;
    float* ctab = (float*)p; p += T_SEQ * 32 * 4;
    float* stab = (float*)p; p += T_SEQ * 32 * 4;
    // total ~94 MB

    rope_tables_kernel<<<256, 256, 0, stream>>>(ctab, stab);
    xcvt_kernel<<<(int)(XSZ / 8 / 256), 256, 0, stream>>>(x, Xf);
    wcvt_kernel<<<dim3(128, 64), 64, 0, stream>>>(Wqkv, Wout, Wqt, Wot);
    qkv_gemm_kernel<<<dim3(64, 24), 256, 0, stream>>>(
        Xf, Wqt, bqkv, ctab, stab, qf, kf, vtb);
    attn_kernel<<<dim3(16, BHN), 256, 0, stream>>>(qf, kf, vtb, ab);
    out_gemm_kernel<<<dim3(64, 8), 256, 0, stream>>>(ab, Wot, bout, out);
}

// Round 5
// 281.233 us; speedup vs baseline: 1.0973x; 1.0477x over previous
//
#include <hip/hip_runtime.h>
#include <math.h>

// Problem constants
#define T_SEQ 2048
#define CDIM  1024
#define NH    16
#define DHD   64
#define BATCH 4
#define MROWS (BATCH * T_SEQ)   // 8192
#define BHN   (BATCH * NH)      // 64

typedef _Float16 f16;
typedef __attribute__((ext_vector_type(8))) _Float16 f16x8;
typedef __attribute__((ext_vector_type(4))) _Float16 f16x4;
typedef __attribute__((ext_vector_type(2))) _Float16 f16x2;
typedef __attribute__((ext_vector_type(2))) __fp16 fp16x2;
typedef __attribute__((ext_vector_type(4))) float f32x4;

__device__ __forceinline__ float fast_exp2(float x) {
#if __has_builtin(__builtin_amdgcn_exp2f)
    return __builtin_amdgcn_exp2f(x);
#else
    return exp2f(x);
#endif
}

__device__ __forceinline__ float fast_rcp(float x) {
#if __has_builtin(__builtin_amdgcn_rcpf)
    return __builtin_amdgcn_rcpf(x);
#else
    return 1.0f / x;
#endif
}

// packed f32x2 -> f16x2 convert (v_cvt_pkrtz_f16_f32)
__device__ __forceinline__ f16x2 cvt_pk_f16(float a, float b) {
    fp16x2 r = __builtin_amdgcn_cvt_pkrtz(a, b);
    return __builtin_bit_cast(f16x2, r);
}

// async global->LDS, 16B per lane; LDS dest = wave-uniform base + lane*16
__device__ __forceinline__ void gl_lds16(const f16* g, f16* l) {
    __builtin_amdgcn_global_load_lds(
        (const __attribute__((address_space(1))) void*)(g),
        (__attribute__((address_space(3))) void*)(l),
        16, 0, 0);
}

// ---------------------------------------------------------------------------
// RoPE trig tables (fp64 math)
// ---------------------------------------------------------------------------
__global__ void rope_tables_kernel(float* __restrict__ ctab, float* __restrict__ stab)
{
    int idx = blockIdx.x * 256 + threadIdx.x;   // 0 .. 2048*32-1
    int t = idx >> 5, i = idx & 31;
    double inv = pow(10000.0, -(double)(2 * i) / 64.0);
    double a = (double)t * inv;
    ctab[idx] = (float)cos(a);
    stab[idx] = (float)sin(a);
}

// ---------------------------------------------------------------------------
// X convert: fp32 [8192][1024] -> f16, same layout. 8 elems/thread.
// ---------------------------------------------------------------------------
__global__ __launch_bounds__(256) void xcvt_kernel(
    const float* __restrict__ X, f16* __restrict__ Xf)
{
    int idx = blockIdx.x * 256 + threadIdx.x;   // 8-elem chunk index
    const float4* src = (const float4*)X + (size_t)idx * 2;
    float4 a = src[0], b = src[1];
    f16x8 o;
    o[0] = (f16)a.x; o[1] = (f16)a.y; o[2] = (f16)a.z; o[3] = (f16)a.w;
    o[4] = (f16)b.x; o[5] = (f16)b.y; o[6] = (f16)b.z; o[7] = (f16)b.w;
    *((f16x8*)Xf + idx) = o;
}

// ---------------------------------------------------------------------------
// W transpose+convert (both weights in one launch):
//   y <  48 : Wqkv [1024][3072] -> Wqt [3072][1024]
//   y >= 48 : Wout [1024][1024] -> Wot [1024][1024]
// ---------------------------------------------------------------------------
__global__ __launch_bounds__(64) void wcvt_kernel(
    const float* __restrict__ Wq, const float* __restrict__ Wo,
    f16* __restrict__ Wqt, f16* __restrict__ Wot)
{
    int lane = threadIdx.x;
    int k0 = blockIdx.x * 8;
    int ny = blockIdx.y;
    const float* W;
    f16* Wt;
    int N, n;
    if (ny < 48) { W = Wq; Wt = Wqt; N = 3072; n = ny * 64 + lane; }
    else         { W = Wo; Wt = Wot; N = 1024; n = (ny - 48) * 64 + lane; }
    f16x8 o;
#pragma unroll
    for (int j = 0; j < 8; j++) o[j] = (f16)W[(size_t)(k0 + j) * N + n];
    *(f16x8*)(Wt + (size_t)n * CDIM + k0) = o;
}

// ---------------------------------------------------------------------------
// f16 MFMA GEMM mainloop v2: C[128x128] = A[128xK] B_t[128xK], K=1024
//  - BK=64 (m97 structure): 32 MFMA per barrier pair, 16 K-steps
//  - LDS XOR-swizzle via PRE-SWIZZLED GLOBAL SOURCE (rule: global_load_lds
//    writes linear; permute the per-lane global chunk instead):
//      stage: lane (srow=lane>>3, schunk=lane&7) loads global chunk
//             schunk^srow of row it*8+srow  -> phys chunk p of row r holds
//             global chunk p ^ (r&7)
//      read:  logical chunk c of row r is at phys c ^ (r&7)
//    Per-16-lane phase of ds_read_b128: 8 distinct 4-bank groups x 2 lanes
//    = 2-way (free). Unswizzled [128][64] would be 16-way, [128][32] 8-way.
// ---------------------------------------------------------------------------
#define GEMM_MAINLOOP(Aimg, Bimg, M0, N0)                                         \
    __shared__ f16 As[128][64], Bs[128][64];                                      \
    const int tid = threadIdx.x, wave = tid >> 6, lane = tid & 63;                \
    const int l16 = lane & 15, quad = lane >> 4;                                  \
    const int wm = wave >> 1, wn = wave & 1;                                      \
    f32x4 acc[4][4];                                                              \
    _Pragma("unroll") for (int i = 0; i < 4; i++)                                 \
        _Pragma("unroll") for (int j = 0; j < 4; j++)                             \
            acc[i][j] = (f32x4){0.f, 0.f, 0.f, 0.f};                              \
    const f16* sbase = (wave < 2) ? (Aimg) : (Bimg);                              \
    f16* lbase = ((wave < 2) ? &As[0][0] : &Bs[0][0]) + (wave & 1) * 4096;        \
    const size_t srow0 = ((wave < 2) ? (size_t)(M0) : (size_t)(N0)) + (wave & 1) * 64; \
    const int srow = lane >> 3, schunk = lane & 7;                                \
    const int gchunk = (schunk ^ srow) << 3;   /* pre-swizzled global col */      \
    for (int k0 = 0; k0 < CDIM; k0 += 64) {                                       \
        _Pragma("unroll") for (int it = 0; it < 8; it++)                          \
            gl_lds16(sbase + (srow0 + it * 8 + srow) * CDIM + k0 + gchunk,        \
                     lbase + it * 512);                                           \
        __syncthreads();                                                          \
        _Pragma("unroll") for (int ks = 0; ks < 2; ks++) {                        \
            f16x8 fa[4], fb[4];                                                   \
            _Pragma("unroll") for (int mi = 0; mi < 4; mi++)                      \
                fa[mi] = *(const f16x8*)                                          \
                    &As[wm * 64 + mi * 16 + l16][((ks * 4 + quad) ^ (l16 & 7)) << 3]; \
            _Pragma("unroll") for (int ni = 0; ni < 4; ni++)                      \
                fb[ni] = *(const f16x8*)                                          \
                    &Bs[wn * 64 + ni * 16 + l16][((ks * 4 + quad) ^ (l16 & 7)) << 3]; \
            _Pragma("unroll") for (int mi = 0; mi < 4; mi++)                      \
                _Pragma("unroll") for (int ni = 0; ni < 4; ni++)                  \
                    acc[mi][ni] = __builtin_amdgcn_mfma_f32_16x16x32_f16(         \
                        fa[mi], fb[ni], acc[mi][ni], 0, 0, 0);                    \
        }                                                                         \
        __syncthreads();                                                          \
    }

// ---------------------------------------------------------------------------
// QKV GEMM (f16 MFMA), fused bias + RoPE; writes q/k in [bh][t][d], and V
// DIRECTLY TRANSPOSED into vt [bh][d][t].
// Q is pre-scaled by (1/8)*log2(e)  -->  attn uses exp2 directly.
// ---------------------------------------------------------------------------
__global__ __launch_bounds__(256) void qkv_gemm_kernel(
    const f16* __restrict__ Xf, const f16* __restrict__ Wt,
    const float* __restrict__ bias,
    const float* __restrict__ ctab, const float* __restrict__ stab,
    f16* __restrict__ qf, f16* __restrict__ kf, f16* __restrict__ vtb)
{
    const int m0 = blockIdx.x * 128;
    const int n0 = blockIdx.y * 128;
    GEMM_MAINLOOP(Xf, Wt, m0, n0)

    const int ncol0 = n0 + wn * 64;            // 64-aligned -> one head group
    const int w = ncol0 >> 10;                 // 0=q 1=k 2=v
    const int h = (ncol0 >> 6) & 15;
    const int b = m0 >> 11;
    const int trow0 = (m0 & 2047) + wm * 64 + quad * 4;
    float bia[4];
#pragma unroll
    for (int ni = 0; ni < 4; ni++) bia[ni] = bias[ncol0 + ni * 16 + l16];

    if (w < 2) {
        f16* oq = w ? kf : qf;
        // q scale folds softmax 1/8 AND log2(e) so attn can use v_exp (2^x)
        const float sc = w ? 1.0f : 0.18033688011112042f;
#pragma unroll
        for (int mi = 0; mi < 4; mi++) {
#pragma unroll
            for (int i = 0; i < 4; i++) {
                int t = trow0 + mi * 16 + i;
                size_t rowoff = ((size_t)(b * NH + h) * T_SEQ + t) * DHD;
#pragma unroll
                for (int np = 0; np < 2; np++) {
                    int d = np * 16 + l16;             // 0..31
                    float v0 = acc[mi][np][i] + bia[np];
                    float v1 = acc[mi][np + 2][i] + bia[np + 2];
                    float c = ctab[(t << 5) + d];
                    float s = stab[(t << 5) + d];
                    oq[rowoff + d]      = (f16)((v0 * c - v1 * s) * sc);
                    oq[rowoff + d + 32] = (f16)((v1 * c + v0 * s) * sc);
                }
            }
        }
    } else {
        // V: store transposed. acc[mi][ni][0..3] are 4 consecutive t for one
        // d -> one f16x4 store per (mi,ni) into vt[bh][d][t].
#pragma unroll
        for (int mi = 0; mi < 4; mi++) {
            const int tb = trow0 + mi * 16;    // includes quad*4; 4-aligned
#pragma unroll
            for (int ni = 0; ni < 4; ni++) {
                const int d = ni * 16 + l16;
                f16x4 pv;
#pragma unroll
                for (int i = 0; i < 4; i++) pv[i] = (f16)(acc[mi][ni][i] + bia[ni]);
                *(f16x4*)(vtb + ((size_t)(b * NH + h) * DHD + d) * T_SEQ + tb) = pv;
            }
        }
    }
}

// ---------------------------------------------------------------------------
// f16 MFMA flash attention v4 (unchanged from R4):
//  - 128-query blocks, 4 waves x 32 queries; grid 16x64 = 1024 blocks
//    = 4 blocks/CU (LDS = 40960B exactly)
//  - K/V: chunk-XOR swizzle; P: row-rotated dword layout (both CF)
//  - exp2-direct softmax, cvt_pkrtz packing, l via MFMA(P, ones)
//  - s_setprio(1) around MFMA clusters; incremental prefetch pointers
//  - XCD-chunked block swizzle
// ---------------------------------------------------------------------------
__global__ __launch_bounds__(256, 4) void attn_kernel(
    const f16* __restrict__ qf, const f16* __restrict__ kf,
    const f16* __restrict__ vt, f16* __restrict__ ab)
{
    __shared__ f16 Kb[2][64][64];     // [buf][key][d]   16384B, chunk-swizzled
    __shared__ f16 Vb[2][64][64];     // [buf][d][key]   16384B, chunk-swizzled
    __shared__ f16 Pb[4][32][32];     // per-wave [query][key%32] 8192B, rotated
    // total 40960B -> exactly 4 blocks/CU

    const int tid  = threadIdx.x;
    const int wave = tid >> 6, lane = tid & 63;
    const int l16  = lane & 15, quad = lane >> 4;

    // XCD-chunked swizzle: flat id -> (qt, bh) so XCD x holds bh in [8x, 8x+8)
    const int flat = blockIdx.x + (blockIdx.y << 4);     // 0..1023
    const int swz  = (flat & 7) * 128 + (flat >> 3);     // bijective (1024%8==0)
    const int qt = swz & 15;                             // 0..15
    const int bh = swz >> 4;                             // 0..63
    const int q0 = qt * 128 + wave * 32;                 // wave's query base

    const f16* kbase = kf + (size_t)bh * T_SEQ * DHD;
    const f16* vbase = vt + (size_t)bh * DHD * T_SEQ;

    // Q B-frags [qsub][ks]: B[n=query=l16][k=d=quad*8+j]
    f16x8 qfr[2][2];
#pragma unroll
    for (int qs = 0; qs < 2; qs++) {
        const f16* qrow = qf + ((size_t)bh * T_SEQ + q0 + qs * 16 + l16) * DHD;
        qfr[qs][0] = *(const f16x8*)(qrow + quad * 8);
        qfr[qs][1] = *(const f16x8*)(qrow + 32 + quad * 8);
    }

    f32x4 o[2][4];      // [qsub][dt], C-layout row=query col=d
    f32x4 lacc[2];      // l partials, same row layout as o
#pragma unroll
    for (int qs = 0; qs < 2; qs++) {
        lacc[qs] = (f32x4){0.f, 0.f, 0.f, 0.f};
#pragma unroll
        for (int dt = 0; dt < 4; dt++) o[qs][dt] = (f32x4){0.f, 0.f, 0.f, 0.f};
    }
    f16x8 ones;
#pragma unroll
    for (int j = 0; j < 8; j++) ones[j] = (f16)1.0f;

    // staging map: 256 threads x 2 rounds x b128 = 8KB per array per tile
    const int srow = tid >> 3;                       // 0..31
    const int scw  = tid & 7;                        // chunk 0..7
    const int scol = scw << 3;                       // global f16 col
    const int swzc = (scw ^ (srow & 7)) << 3;        // swizzled LDS f16 col

    // P layout: row-rotation (in dwords) for bank-conflict-free b64 access
    const int prot = l16 & 14;                       // rotation, dwords (even)

    // per-thread staging pointers (incremented, not recomputed)
    const f16* kp = kbase + (size_t)srow * DHD + scol;
    const f16* vp = vbase + (size_t)srow * T_SEQ + scol;

    f16x8 kreg[2], vreg[2];
#pragma unroll
    for (int r = 0; r < 2; r++) {
        kreg[r] = *(const f16x8*)(kp + (size_t)(r * 32) * DHD);
        vreg[r] = *(const f16x8*)(vp + (size_t)(r * 32) * T_SEQ);
    }
#pragma unroll
    for (int r = 0; r < 2; r++) {
        *(f16x8*)&Kb[0][srow + r * 32][swzc] = kreg[r];
        *(f16x8*)&Vb[0][srow + r * 32][swzc] = vreg[r];
    }
    const f16* kq = kp + 64 * DHD;   // next-tile pointers
    const f16* vq = vp + 64;
    __syncthreads();

    for (int kt = 0; kt < 32; kt++) {
        const int buf = kt & 1;
        if (kt < 31) {   // prefetch next tile into registers (no wait)
#pragma unroll
            for (int r = 0; r < 2; r++) {
                kreg[r] = *(const f16x8*)(kq + (size_t)(r * 32) * DHD);
                vreg[r] = *(const f16x8*)(vq + (size_t)(r * 32) * T_SEQ);
            }
            kq += 64 * DHD;
            vq += 64;
        }

#pragma unroll
        for (int half = 0; half < 2; half++) {
            // ---- S^T for 32 keys x 32 queries ----
            f32x4 sc[2][2];   // [keysub][qsub]
#pragma unroll
            for (int k2 = 0; k2 < 2; k2++)
#pragma unroll
                for (int qs = 0; qs < 2; qs++) sc[k2][qs] = (f32x4){0.f, 0.f, 0.f, 0.f};
            __builtin_amdgcn_s_setprio(1);
#pragma unroll
            for (int k2 = 0; k2 < 2; k2++) {
                const int keyt = half * 2 + k2;
#pragma unroll
                for (int ks = 0; ks < 2; ks++) {
                    const int kc = ((ks * 4 + quad) ^ (l16 & 7)) << 3;
                    f16x8 kfr = *(const f16x8*)&Kb[buf][keyt * 16 + l16][kc];
#pragma unroll
                    for (int qs = 0; qs < 2; qs++)
                        sc[k2][qs] = __builtin_amdgcn_mfma_f32_16x16x32_f16(
                            kfr, qfr[qs][ks], sc[k2][qs], 0, 0, 0);
                }
            }
            __builtin_amdgcn_s_setprio(0);
            // ---- exp2 (log2e pre-folded), pack P via cvt_pkrtz ----
            // write: logical dword = 8*k2 + 2*quad (keys k2*16+quad*4..+3),
            // phys dword = (log + prot) & 15 -> conflict-free b64 store
#pragma unroll
            for (int k2 = 0; k2 < 2; k2++) {
#pragma unroll
                for (int qs = 0; qs < 2; qs++) {
                    f16x2 pa = cvt_pk_f16(
                        fast_exp2(sc[k2][qs][0]), fast_exp2(sc[k2][qs][1]));
                    f16x2 pb = cvt_pk_f16(
                        fast_exp2(sc[k2][qs][2]), fast_exp2(sc[k2][qs][3]));
                    f16x4 pv;
                    ((f16x2*)&pv)[0] = pa;
                    ((f16x2*)&pv)[1] = pb;
                    const int pc = (((k2 << 3) + (quad << 1) + prot) & 15) << 1;
                    *(f16x4*)&Pb[wave][qs * 16 + l16][pc] = pv;
                }
            }
            // ---- P frags (2x b64, same rotation); l += P*ones; PV ----
            const int pr0 = (((quad << 2)     + prot) & 15) << 1;
            const int pr1 = (((quad << 2) + 2 + prot) & 15) << 1;
            f16x8 pfr[2];
#pragma unroll
            for (int qs = 0; qs < 2; qs++) {
                f16x4 plo = *(const f16x4*)&Pb[wave][qs * 16 + l16][pr0];
                f16x4 phi = *(const f16x4*)&Pb[wave][qs * 16 + l16][pr1];
                f16x8 pf;
                pf[0] = plo[0]; pf[1] = plo[1]; pf[2] = plo[2]; pf[3] = plo[3];
                pf[4] = phi[0]; pf[5] = phi[1]; pf[6] = phi[2]; pf[7] = phi[3];
                pfr[qs] = pf;
            }
            __builtin_amdgcn_s_setprio(1);
#pragma unroll
            for (int qs = 0; qs < 2; qs++)
                lacc[qs] = __builtin_amdgcn_mfma_f32_16x16x32_f16(
                    pfr[qs], ones, lacc[qs], 0, 0, 0);
#pragma unroll
            for (int dt = 0; dt < 4; dt++) {
                const int vc = ((half * 4 + quad) ^ (l16 & 7)) << 3;
                f16x8 vfr = *(const f16x8*)&Vb[buf][dt * 16 + l16][vc];
#pragma unroll
                for (int qs = 0; qs < 2; qs++)
                    o[qs][dt] = __builtin_amdgcn_mfma_f32_16x16x32_f16(
                        pfr[qs], vfr, o[qs][dt], 0, 0, 0);
            }
            __builtin_amdgcn_s_setprio(0);
        }

        if (kt < 31) {   // write prefetched tile into the other buffer
#pragma unroll
            for (int r = 0; r < 2; r++) {
                *(f16x8*)&Kb[buf ^ 1][srow + r * 32][swzc] = kreg[r];
                *(f16x8*)&Vb[buf ^ 1][srow + r * 32][swzc] = vreg[r];
            }
        }
        __syncthreads();
    }

    // ---- epilogue: normalize by lane-local 1/l, write ab[q][h*64+d] ----
    const int b = bh >> 4, h = bh & 15;
#pragma unroll
    for (int qs = 0; qs < 2; qs++) {
#pragma unroll
        for (int i = 0; i < 4; i++) {
            float iv = fast_rcp(lacc[qs][i]);
            int m = b * T_SEQ + qt * 128 + wave * 32 + qs * 16 + quad * 4 + i;
#pragma unroll
            for (int dt = 0; dt < 4; dt++)
                ab[(size_t)m * CDIM + h * 64 + dt * 16 + l16] = (f16)(o[qs][dt][i] * iv);
        }
    }
}

// ---------------------------------------------------------------------------
// Output GEMM (f16 MFMA): out = ab @ Wout + bias (fp32 out)
// ---------------------------------------------------------------------------
__global__ __launch_bounds__(256) void out_gemm_kernel(
    const f16* __restrict__ Ab, const f16* __restrict__ Wt,
    const float* __restrict__ bias, float* __restrict__ out)
{
    const int m0 = blockIdx.x * 128;
    const int n0 = blockIdx.y * 128;
    GEMM_MAINLOOP(Ab, Wt, m0, n0)

    const int ncol0 = n0 + wn * 64;
    float bia[4];
#pragma unroll
    for (int ni = 0; ni < 4; ni++) bia[ni] = bias[ncol0 + ni * 16 + l16];
#pragma unroll
    for (int mi = 0; mi < 4; mi++) {
#pragma unroll
        for (int i = 0; i < 4; i++) {
            int m = m0 + wm * 64 + mi * 16 + quad * 4 + i;
#pragma unroll
            for (int ni = 0; ni < 4; ni++)
                out[(size_t)m * CDIM + ncol0 + ni * 16 + l16] = acc[mi][ni][i] + bia[ni];
        }
    }
}

// ---------------------------------------------------------------------------
extern "C" void kernel_launch(void* const* d_in, const int* in_sizes, int n_in,
                              void* d_out, int out_size, void* d_ws, size_t ws_size,
                              hipStream_t stream)
{
    const float* x    = (const float*)d_in[0];
    const float* Wqkv = (const float*)d_in[1];
    const float* bqkv = (const float*)d_in[2];
    const float* Wout = (const float*)d_in[3];
    const float* bout = (const float*)d_in[4];
    float* out = (float*)d_out;

    const size_t XSZ  = (size_t)MROWS * CDIM;        // 8,388,608
    const size_t WQSZ = (size_t)3072 * CDIM;         // 3,145,728
    const size_t WOSZ = (size_t)CDIM * CDIM;         // 1,048,576
    const size_t QSZ  = (size_t)BHN * T_SEQ * DHD;   // 8,388,608

    char* p = (char*)d_ws;
    f16* Xf  = (f16*)p; p += XSZ * 2;
    f16* Wqt = (f16*)p; p += WQSZ * 2;
    f16* Wot = (f16*)p; p += WOSZ * 2;
    f16* qf  = (f16*)p; p += QSZ * 2;
    f16* kf  = (f16*)p; p += QSZ * 2;
    f16* vtb = (f16*)p; p += QSZ * 2;
    f16* ab  = (f16*)p; p += QSZ * 2;
    float* ctab = (float*)p; p += T_SEQ * 32 * 4;
    float* stab = (float*)p; p += T_SEQ * 32 * 4;
    // total ~94 MB

    rope_tables_kernel<<<256, 256, 0, stream>>>(ctab, stab);
    xcvt_kernel<<<(int)(XSZ / 8 / 256), 256, 0, stream>>>(x, Xf);
    wcvt_kernel<<<dim3(128, 64), 64, 0, stream>>>(Wqkv, Wout, Wqt, Wot);
    qkv_gemm_kernel<<<dim3(64, 24), 256, 0, stream>>>(
        Xf, Wqt, bqkv, ctab, stab, qf, kf, vtb);
    attn_kernel<<<dim3(16, BHN), 256, 0, stream>>>(qf, kf, vtb, ab);
    out_gemm_kernel<<<dim3(64, 8), 256, 0, stream>>>(ab, Wot, bout, out);
}

// Round 6
// 276.400 us; speedup vs baseline: 1.1165x; 1.0175x over previous
//
#include <hip/hip_runtime.h>
#include <math.h>

// Problem constants
#define T_SEQ 2048
#define CDIM  1024
#define NH    16
#define DHD   64
#define BATCH 4
#define MROWS (BATCH * T_SEQ)   // 8192
#define BHN   (BATCH * NH)      // 64

typedef _Float16 f16;
typedef __attribute__((ext_vector_type(8))) _Float16 f16x8;
typedef __attribute__((ext_vector_type(4))) _Float16 f16x4;
typedef __attribute__((ext_vector_type(2))) _Float16 f16x2;
typedef __attribute__((ext_vector_type(2))) __fp16 fp16x2;
typedef __attribute__((ext_vector_type(4))) float f32x4;

__device__ __forceinline__ float fast_exp2(float x) {
#if __has_builtin(__builtin_amdgcn_exp2f)
    return __builtin_amdgcn_exp2f(x);
#else
    return exp2f(x);
#endif
}

__device__ __forceinline__ float fast_rcp(float x) {
#if __has_builtin(__builtin_amdgcn_rcpf)
    return __builtin_amdgcn_rcpf(x);
#else
    return 1.0f / x;
#endif
}

// packed f32x2 -> f16x2 convert (v_cvt_pkrtz_f16_f32)
__device__ __forceinline__ f16x2 cvt_pk_f16(float a, float b) {
    fp16x2 r = __builtin_amdgcn_cvt_pkrtz(a, b);
    return __builtin_bit_cast(f16x2, r);
}

// async global->LDS, 16B per lane; LDS dest = wave-uniform base + lane*16
__device__ __forceinline__ void gl_lds16(const f16* g, f16* l) {
    __builtin_amdgcn_global_load_lds(
        (const __attribute__((address_space(1))) void*)(g),
        (__attribute__((address_space(3))) void*)(l),
        16, 0, 0);
}

// ---------------------------------------------------------------------------
// Prep kernel (one launch): RoPE tables + X fp32->f16 + both W transposes
//   blocks [0,256):        rope tables (fp64 math)
//   blocks [256,4352):     xcvt
//   blocks [4352,6400):    wcvt (4 x 64-lane jobs per block)
// ---------------------------------------------------------------------------
__global__ __launch_bounds__(256) void prep_kernel(
    const float* __restrict__ X, f16* __restrict__ Xf,
    const float* __restrict__ Wq, const float* __restrict__ Wo,
    f16* __restrict__ Wqt, f16* __restrict__ Wot,
    float* __restrict__ ctab, float* __restrict__ stab)
{
    const int bx = blockIdx.x;
    if (bx < 256) {
        int idx = bx * 256 + threadIdx.x;   // 0 .. 2048*32-1
        int t = idx >> 5, i = idx & 31;
        double inv = pow(10000.0, -(double)(2 * i) / 64.0);
        double a = (double)t * inv;
        ctab[idx] = (float)cos(a);
        stab[idx] = (float)sin(a);
    } else if (bx < 4352) {
        int idx = (bx - 256) * 256 + threadIdx.x;   // 8-elem chunk index
        const float4* src = (const float4*)X + (size_t)idx * 2;
        float4 a = src[0], b = src[1];
        f16x8 o;
        o[0] = (f16)a.x; o[1] = (f16)a.y; o[2] = (f16)a.z; o[3] = (f16)a.w;
        o[4] = (f16)b.x; o[5] = (f16)b.y; o[6] = (f16)b.z; o[7] = (f16)b.w;
        *((f16x8*)Xf + idx) = o;
    } else {
        const int sub = threadIdx.x >> 6, lane = threadIdx.x & 63;
        const int id = (bx - 4352) * 4 + sub;   // 0..8191
        const int k0 = (id & 127) * 8;
        const int ny = id >> 7;                 // 0..63
        const float* W;
        f16* Wt;
        int N, n;
        if (ny < 48) { W = Wq; Wt = Wqt; N = 3072; n = ny * 64 + lane; }
        else         { W = Wo; Wt = Wot; N = 1024; n = (ny - 48) * 64 + lane; }
        f16x8 o;
#pragma unroll
        for (int j = 0; j < 8; j++) o[j] = (f16)W[(size_t)(k0 + j) * N + n];
        *(f16x8*)(Wt + (size_t)n * CDIM + k0) = o;
    }
}

// ---------------------------------------------------------------------------
// f16 MFMA GEMM mainloop v2: C[128x128] = A[128xK] B_t[128xK], K=1024
//  - BK=64, LDS XOR-swizzle via pre-swizzled global source (see R5 notes)
// ---------------------------------------------------------------------------
#define GEMM_MAINLOOP(Aimg, Bimg, M0, N0)                                         \
    __shared__ f16 As[128][64], Bs[128][64];                                      \
    const int tid = threadIdx.x, wave = tid >> 6, lane = tid & 63;                \
    const int l16 = lane & 15, quad = lane >> 4;                                  \
    const int wm = wave >> 1, wn = wave & 1;                                      \
    f32x4 acc[4][4];                                                              \
    _Pragma("unroll") for (int i = 0; i < 4; i++)                                 \
        _Pragma("unroll") for (int j = 0; j < 4; j++)                             \
            acc[i][j] = (f32x4){0.f, 0.f, 0.f, 0.f};                              \
    const f16* sbase = (wave < 2) ? (Aimg) : (Bimg);                              \
    f16* lbase = ((wave < 2) ? &As[0][0] : &Bs[0][0]) + (wave & 1) * 4096;        \
    const size_t srow0 = ((wave < 2) ? (size_t)(M0) : (size_t)(N0)) + (wave & 1) * 64; \
    const int srow = lane >> 3, schunk = lane & 7;                                \
    const int gchunk = (schunk ^ srow) << 3;   /* pre-swizzled global col */      \
    for (int k0 = 0; k0 < CDIM; k0 += 64) {                                       \
        _Pragma("unroll") for (int it = 0; it < 8; it++)                          \
            gl_lds16(sbase + (srow0 + it * 8 + srow) * CDIM + k0 + gchunk,        \
                     lbase + it * 512);                                           \
        __syncthreads();                                                          \
        _Pragma("unroll") for (int ks = 0; ks < 2; ks++) {                        \
            f16x8 fa[4], fb[4];                                                   \
            _Pragma("unroll") for (int mi = 0; mi < 4; mi++)                      \
                fa[mi] = *(const f16x8*)                                          \
                    &As[wm * 64 + mi * 16 + l16][((ks * 4 + quad) ^ (l16 & 7)) << 3]; \
            _Pragma("unroll") for (int ni = 0; ni < 4; ni++)                      \
                fb[ni] = *(const f16x8*)                                          \
                    &Bs[wn * 64 + ni * 16 + l16][((ks * 4 + quad) ^ (l16 & 7)) << 3]; \
            _Pragma("unroll") for (int mi = 0; mi < 4; mi++)                      \
                _Pragma("unroll") for (int ni = 0; ni < 4; ni++)                  \
                    acc[mi][ni] = __builtin_amdgcn_mfma_f32_16x16x32_f16(         \
                        fa[mi], fb[ni], acc[mi][ni], 0, 0, 0);                    \
        }                                                                         \
        __syncthreads();                                                          \
    }

// ---------------------------------------------------------------------------
// QKV GEMM (f16 MFMA), fused bias + RoPE; writes q/k in [bh][t][d], and V
// DIRECTLY TRANSPOSED into vt [bh][d][t].
// Q is pre-scaled by (1/8)*log2(e)  -->  attn uses exp2 directly.
// ---------------------------------------------------------------------------
__global__ __launch_bounds__(256) void qkv_gemm_kernel(
    const f16* __restrict__ Xf, const f16* __restrict__ Wt,
    const float* __restrict__ bias,
    const float* __restrict__ ctab, const float* __restrict__ stab,
    f16* __restrict__ qf, f16* __restrict__ kf, f16* __restrict__ vtb)
{
    const int m0 = blockIdx.x * 128;
    const int n0 = blockIdx.y * 128;
    GEMM_MAINLOOP(Xf, Wt, m0, n0)

    const int ncol0 = n0 + wn * 64;            // 64-aligned -> one head group
    const int w = ncol0 >> 10;                 // 0=q 1=k 2=v
    const int h = (ncol0 >> 6) & 15;
    const int b = m0 >> 11;
    const int trow0 = (m0 & 2047) + wm * 64 + quad * 4;
    float bia[4];
#pragma unroll
    for (int ni = 0; ni < 4; ni++) bia[ni] = bias[ncol0 + ni * 16 + l16];

    if (w < 2) {
        f16* oq = w ? kf : qf;
        // q scale folds softmax 1/8 AND log2(e) so attn can use v_exp (2^x)
        const float sc = w ? 1.0f : 0.18033688011112042f;
#pragma unroll
        for (int mi = 0; mi < 4; mi++) {
#pragma unroll
            for (int i = 0; i < 4; i++) {
                int t = trow0 + mi * 16 + i;
                size_t rowoff = ((size_t)(b * NH + h) * T_SEQ + t) * DHD;
#pragma unroll
                for (int np = 0; np < 2; np++) {
                    int d = np * 16 + l16;             // 0..31
                    float v0 = acc[mi][np][i] + bia[np];
                    float v1 = acc[mi][np + 2][i] + bia[np + 2];
                    float c = ctab[(t << 5) + d];
                    float s = stab[(t << 5) + d];
                    oq[rowoff + d]      = (f16)((v0 * c - v1 * s) * sc);
                    oq[rowoff + d + 32] = (f16)((v1 * c + v0 * s) * sc);
                }
            }
        }
    } else {
        // V: store transposed. acc[mi][ni][0..3] are 4 consecutive t for one
        // d -> one f16x4 store per (mi,ni) into vt[bh][d][t].
#pragma unroll
        for (int mi = 0; mi < 4; mi++) {
            const int tb = trow0 + mi * 16;    // includes quad*4; 4-aligned
#pragma unroll
            for (int ni = 0; ni < 4; ni++) {
                const int d = ni * 16 + l16;
                f16x4 pv;
#pragma unroll
                for (int i = 0; i < 4; i++) pv[i] = (f16)(acc[mi][ni][i] + bia[ni]);
                *(f16x4*)(vtb + ((size_t)(b * NH + h) * DHD + d) * T_SEQ + tb) = pv;
            }
        }
    }
}

// ---------------------------------------------------------------------------
// f16 MFMA flash attention v5 — LDS-traffic-minimized:
//  - P NEVER touches LDS: S^T C-layout (lane: col=query, rows=key quad*4+i)
//    IS the A-fragment of mfma_f32_16x16x16_f16 (k=quad*4+j). PV + l use
//    K=16 MFMAs straight from registers. (removes 16 b64 LDS ops/wave/tile)
//  - K/V staged via global_load_lds with pre-swizzled global source
//    (same chunk-XOR involution as before -> identical LDS layout, read
//    swizzles unchanged; removes 4 b128 ds_writes + prefetch VALU)
//  - LDS 32KB (Kb+Vb only), 4 blocks/CU; one barrier per tile
//  - exp2-direct softmax (log2e pre-folded in Q), cvt_pkrtz packing
//  - XCD-chunked block swizzle; s_setprio around MFMA clusters
// ---------------------------------------------------------------------------
__global__ __launch_bounds__(256, 4) void attn_kernel(
    const f16* __restrict__ qf, const f16* __restrict__ kf,
    const f16* __restrict__ vt, f16* __restrict__ ab)
{
    __shared__ f16 Kb[2][64][64];     // [buf][key][d]   16384B, chunk-swizzled
    __shared__ f16 Vb[2][64][64];     // [buf][d][key]   16384B, chunk-swizzled

    const int tid  = threadIdx.x;
    const int wave = tid >> 6, lane = tid & 63;
    const int l16  = lane & 15, quad = lane >> 4;

    // XCD-chunked swizzle: flat id -> (qt, bh) so XCD x holds bh in [8x, 8x+8)
    const int flat = blockIdx.x + (blockIdx.y << 4);     // 0..1023
    const int swz  = (flat & 7) * 128 + (flat >> 3);     // bijective (1024%8==0)
    const int qt = swz & 15;                             // 0..15
    const int bh = swz >> 4;                             // 0..63
    const int q0 = qt * 128 + wave * 32;                 // wave's query base

    const f16* kbase = kf + (size_t)bh * T_SEQ * DHD;
    const f16* vbase = vt + (size_t)bh * DHD * T_SEQ;

    // Q B-frags [qsub][ks]: B[n=query=l16][k=d=quad*8+j]
    f16x8 qfr[2][2];
#pragma unroll
    for (int qs = 0; qs < 2; qs++) {
        const f16* qrow = qf + ((size_t)bh * T_SEQ + q0 + qs * 16 + l16) * DHD;
        qfr[qs][0] = *(const f16x8*)(qrow + quad * 8);
        qfr[qs][1] = *(const f16x8*)(qrow + 32 + quad * 8);
    }

    f32x4 o[2][4];      // [qsub][dt], C-layout row=query col=d
    f32x4 lacc[2];      // l partials, same row layout as o
#pragma unroll
    for (int qs = 0; qs < 2; qs++) {
        lacc[qs] = (f32x4){0.f, 0.f, 0.f, 0.f};
#pragma unroll
        for (int dt = 0; dt < 4; dt++) o[qs][dt] = (f32x4){0.f, 0.f, 0.f, 0.f};
    }
    f16x4 ones4;
#pragma unroll
    for (int j = 0; j < 4; j++) ones4[j] = (f16)1.0f;

    // staging map: thread covers row srow(+32), chunk schunk; the GLOBAL
    // column is pre-XORed so the linear global_load_lds dest yields
    // phys chunk p of row r = global chunk p ^ (r&7)
    const int srow = tid >> 3;                       // 0..31
    const int schunk = tid & 7;
    const int gcol = (schunk ^ (srow & 7)) << 3;

#define STAGE(t, b)                                                               \
    {                                                                             \
        const f16* kg = kbase + ((size_t)(t) * 64 + srow) * DHD + gcol;           \
        const f16* vg = vbase + (size_t)srow * T_SEQ + (t) * 64 + gcol;           \
        f16* kl = &Kb[b][wave * 8][0];                                            \
        f16* vl = &Vb[b][wave * 8][0];                                            \
        gl_lds16(kg, kl);                                                         \
        gl_lds16(kg + 32 * DHD, kl + 32 * 64);                                    \
        gl_lds16(vg, vl);                                                         \
        gl_lds16(vg + (size_t)32 * T_SEQ, vl + 32 * 64);                          \
    }

    STAGE(0, 0)
    __syncthreads();

    for (int kt = 0; kt < 32; kt++) {
        const int buf = kt & 1;
        if (kt < 31) STAGE(kt + 1, buf ^ 1)

#pragma unroll
        for (int half = 0; half < 2; half++) {
            // ---- S^T for 32 keys x 32 queries (K=32 MFMA) ----
            f32x4 sc[2][2];   // [keysub][qsub]
#pragma unroll
            for (int k2 = 0; k2 < 2; k2++)
#pragma unroll
                for (int qs = 0; qs < 2; qs++) sc[k2][qs] = (f32x4){0.f, 0.f, 0.f, 0.f};
            __builtin_amdgcn_s_setprio(1);
#pragma unroll
            for (int k2 = 0; k2 < 2; k2++) {
                const int keyt = half * 2 + k2;
#pragma unroll
                for (int ks = 0; ks < 2; ks++) {
                    const int kc = ((ks * 4 + quad) ^ (l16 & 7)) << 3;
                    f16x8 kfr = *(const f16x8*)&Kb[buf][keyt * 16 + l16][kc];
#pragma unroll
                    for (int qs = 0; qs < 2; qs++)
                        sc[k2][qs] = __builtin_amdgcn_mfma_f32_16x16x32_f16(
                            kfr, qfr[qs][ks], sc[k2][qs], 0, 0, 0);
                }
            }
            __builtin_amdgcn_s_setprio(0);
            // ---- exp2 + pack: P stays in registers as K=16 A-frags ----
            f16x4 pp[2][2];   // [k2][qs]
#pragma unroll
            for (int k2 = 0; k2 < 2; k2++) {
#pragma unroll
                for (int qs = 0; qs < 2; qs++) {
                    ((f16x2*)&pp[k2][qs])[0] = cvt_pk_f16(
                        fast_exp2(sc[k2][qs][0]), fast_exp2(sc[k2][qs][1]));
                    ((f16x2*)&pp[k2][qs])[1] = cvt_pk_f16(
                        fast_exp2(sc[k2][qs][2]), fast_exp2(sc[k2][qs][3]));
                }
            }
            // ---- l += P*ones and PV, all K=16 MFMA from registers ----
            __builtin_amdgcn_s_setprio(1);
#pragma unroll
            for (int qs = 0; qs < 2; qs++)
#pragma unroll
                for (int k2 = 0; k2 < 2; k2++)
                    lacc[qs] = __builtin_amdgcn_mfma_f32_16x16x16f16(
                        pp[k2][qs], ones4, lacc[qs], 0, 0, 0);
#pragma unroll
            for (int dt = 0; dt < 4; dt++) {
#pragma unroll
                for (int c = 0; c < 2; c++) {
                    const int vc = ((half * 4 + c * 2 + (quad >> 1)) ^ (l16 & 7)) * 8
                                 + (quad & 1) * 4;
                    f16x4 vfr = *(const f16x4*)&Vb[buf][dt * 16 + l16][vc];
#pragma unroll
                    for (int qs = 0; qs < 2; qs++)
                        o[qs][dt] = __builtin_amdgcn_mfma_f32_16x16x16f16(
                            pp[c][qs], vfr, o[qs][dt], 0, 0, 0);
                }
            }
            __builtin_amdgcn_s_setprio(0);
        }

        if (kt < 31) __syncthreads();
    }
#undef STAGE

    // ---- epilogue: normalize by lane-local 1/l, write ab[q][h*64+d] ----
    const int b = bh >> 4, h = bh & 15;
#pragma unroll
    for (int qs = 0; qs < 2; qs++) {
#pragma unroll
        for (int i = 0; i < 4; i++) {
            float iv = fast_rcp(lacc[qs][i]);
            int m = b * T_SEQ + qt * 128 + wave * 32 + qs * 16 + quad * 4 + i;
#pragma unroll
            for (int dt = 0; dt < 4; dt++)
                ab[(size_t)m * CDIM + h * 64 + dt * 16 + l16] = (f16)(o[qs][dt][i] * iv);
        }
    }
}

// ---------------------------------------------------------------------------
// Output GEMM (f16 MFMA): out = ab @ Wout + bias (fp32 out)
// ---------------------------------------------------------------------------
__global__ __launch_bounds__(256) void out_gemm_kernel(
    const f16* __restrict__ Ab, const f16* __restrict__ Wt,
    const float* __restrict__ bias, float* __restrict__ out)
{
    const int m0 = blockIdx.x * 128;
    const int n0 = blockIdx.y * 128;
    GEMM_MAINLOOP(Ab, Wt, m0, n0)

    const int ncol0 = n0 + wn * 64;
    float bia[4];
#pragma unroll
    for (int ni = 0; ni < 4; ni++) bia[ni] = bias[ncol0 + ni * 16 + l16];
#pragma unroll
    for (int mi = 0; mi < 4; mi++) {
#pragma unroll
        for (int i = 0; i < 4; i++) {
            int m = m0 + wm * 64 + mi * 16 + quad * 4 + i;
#pragma unroll
            for (int ni = 0; ni < 4; ni++)
                out[(size_t)m * CDIM + ncol0 + ni * 16 + l16] = acc[mi][ni][i] + bia[ni];
        }
    }
}

// ---------------------------------------------------------------------------
extern "C" void kernel_launch(void* const* d_in, const int* in_sizes, int n_in,
                              void* d_out, int out_size, void* d_ws, size_t ws_size,
                              hipStream_t stream)
{
    const float* x    = (const float*)d_in[0];
    const float* Wqkv = (const float*)d_in[1];
    const float* bqkv = (const float*)d_in[2];
    const float* Wout = (const float*)d_in[3];
    const float* bout = (const float*)d_in[4];
    float* out = (float*)d_out;

    const size_t XSZ  = (size_t)MROWS * CDIM;        // 8,388,608
    const size_t WQSZ = (size_t)3072 * CDIM;         // 3,145,728
    const size_t WOSZ = (size_t)CDIM * CDIM;         // 1,048,576
    const size_t QSZ  = (size_t)BHN * T_SEQ * DHD;   // 8,388,608

    char* p = (char*)d_ws;
    f16* Xf  = (f16*)p; p += XSZ * 2;
    f16* Wqt = (f16*)p; p += WQSZ * 2;
    f16* Wot = (f16*)p; p += WOSZ * 2;
    f16* qf  = (f16*)p; p += QSZ * 2;
    f16* kf  = (f16*)p; p += QSZ * 2;
    f16* vtb = (f16*)p; p += QSZ * 2;
    f16* ab  = (f16*)p; p += QSZ * 2;
    float* ctab = (float*)p; p += T_SEQ * 32 * 4;
    float* stab = (float*)p; p += T_SEQ * 32 * 4;
    // total ~94 MB

    prep_kernel<<<6400, 256, 0, stream>>>(x, Xf, Wqkv, Wout, Wqt, Wot, ctab, stab);
    qkv_gemm_kernel<<<dim3(64, 24), 256, 0, stream>>>(
        Xf, Wqt, bqkv, ctab, stab, qf, kf, vtb);
    attn_kernel<<<dim3(16, BHN), 256, 0, stream>>>(qf, kf, vtb, ab);
    out_gemm_kernel<<<dim3(64, 8), 256, 0, stream>>>(ab, Wot, bout, out);
}